// Round 17
// baseline (908.281 us; speedup 1.0000x reference)
//
#include <hip/hip_runtime.h>
#include <stdint.h>

typedef unsigned short u16;
typedef unsigned int   u32;

typedef __attribute__((ext_vector_type(8))) __bf16 bf16x8;
typedef __attribute__((ext_vector_type(4))) float  f32x4;

#define GLD_LDS(g, l) __builtin_amdgcn_global_load_lds( \
    (__attribute__((address_space(1))) void*)(g),        \
    (__attribute__((address_space(3))) void*)(l), 16, 0, 0)

__device__ __forceinline__ float bf2f(u16 h) {
    union { u32 u; float f; } c; c.u = ((u32)h) << 16; return c.f;
}
__device__ __forceinline__ u16 f2bf(float f) {
    union { float f; u32 u; } c; c.f = f;
    return (u16)((c.u + 0x7FFFu + ((c.u >> 16) & 1u)) >> 16);
}
__device__ __forceinline__ u32 pack2(float a, float b) {
    return (u32)f2bf(a) | ((u32)f2bf(b) << 16);
}
__device__ __forceinline__ uint4 pack8(float4 a, float4 b) {
    return make_uint4(pack2(a.x, a.y), pack2(a.z, a.w), pack2(b.x, b.y), pack2(b.z, b.w));
}
__device__ __forceinline__ void unpack8(uint4 u, float v[8]) {
    v[0] = bf2f((u16)(u.x & 0xffff)); v[1] = bf2f((u16)(u.x >> 16));
    v[2] = bf2f((u16)(u.y & 0xffff)); v[3] = bf2f((u16)(u.y >> 16));
    v[4] = bf2f((u16)(u.z & 0xffff)); v[5] = bf2f((u16)(u.z >> 16));
    v[6] = bf2f((u16)(u.w & 0xffff)); v[7] = bf2f((u16)(u.w >> 16));
}
__device__ __forceinline__ float wsum(float v) {
#pragma unroll
    for (int o = 32; o > 0; o >>= 1) v += __shfl_xor(v, o, 64);
    return v;
}
// fast tanh-form GELU: max abs err ~3e-3 (<< tolerance), saturates correctly
__device__ __forceinline__ float fast_gelu(float x) {
    const float u = x * (1.f + 0.044715f * x * x);
    return x / (1.f + __expf(-1.5957691216f * u));
}

// ---------------- f32 -> bf16 convert, batched over z ----------------
__global__ __launch_bounds__(256)
void cvt4_kernel(const float* __restrict__ a, const float* __restrict__ b,
                 const float* __restrict__ c, const float* __restrict__ d,
                 u16* __restrict__ oa, u16* __restrict__ ob,
                 u16* __restrict__ oc, u16* __restrict__ od, int n8)
{
    const int i = blockIdx.x * 256 + threadIdx.x;
    if (i >= n8) return;
    const int z = blockIdx.y;
    const float* in = (z == 0) ? a : (z == 1) ? b : (z == 2) ? c : d;
    u16* out = (z == 0) ? oa : (z == 1) ? ob : (z == 2) ? oc : od;
    const float* p = in + (size_t)i * 8;
    float4 u = *(const float4*)p, v = *(const float4*)(p + 4);
    *(uint4*)(out + (size_t)i * 8) = pack8(u, v);
}
__global__ __launch_bounds__(256)
void cvt3_kernel(const float* __restrict__ a, const float* __restrict__ b,
                 const float* __restrict__ c,
                 u16* __restrict__ oa, u16* __restrict__ ob, u16* __restrict__ oc, int n8)
{
    const int i = blockIdx.x * 256 + threadIdx.x;
    if (i >= n8) return;
    const int z = blockIdx.y;
    const float* in = (z == 0) ? a : (z == 1) ? b : c;
    u16* out = (z == 0) ? oa : (z == 1) ? ob : oc;
    const float* p = in + (size_t)i * 8;
    float4 u = *(const float4*)p, v = *(const float4*)(p + 4);
    *(uint4*)(out + (size_t)i * 8) = pack8(u, v);
}

// ---------------- LayerNorm core ----------------
template<bool IN16, bool RAW>
__device__ __forceinline__ void ln_body(const void* in, u16* out,
                                        const float* g, const float* be, u16* raw_out)
{
    const int lane = threadIdx.x & 63;
    const size_t row = (size_t)blockIdx.x * 4 + (threadIdx.x >> 6);
    const size_t base = row * 512 + lane * 8;
    float v[8];
    if constexpr (IN16) {
        unpack8(*(const uint4*)((const u16*)in + base), v);
    } else {
        const float* p = (const float*)in + base;
        float4 a = *(const float4*)p, b = *(const float4*)(p + 4);
        v[0]=a.x; v[1]=a.y; v[2]=a.z; v[3]=a.w; v[4]=b.x; v[5]=b.y; v[6]=b.z; v[7]=b.w;
    }
    if constexpr (RAW) {
        u32 ro[4];
#pragma unroll
        for (int i = 0; i < 4; ++i) ro[i] = pack2(v[2*i], v[2*i+1]);
        *(uint4*)(raw_out + base) = make_uint4(ro[0], ro[1], ro[2], ro[3]);
    }
    float s = 0.f, ss = 0.f;
#pragma unroll
    for (int i = 0; i < 8; ++i) { s += v[i]; ss += v[i] * v[i]; }
    s = wsum(s); ss = wsum(ss);
    const float mean = s * (1.f / 512.f);
    const float rstd = rsqrtf(ss * (1.f / 512.f) - mean * mean + 1e-5f);
    const float* gp = g + lane * 8;
    const float* bp = be + lane * 8;
    u32 o[4];
#pragma unroll
    for (int i = 0; i < 4; ++i) {
        u16 lo = f2bf((v[2*i]   - mean) * rstd * gp[2*i]   + bp[2*i]);
        u16 hi = f2bf((v[2*i+1] - mean) * rstd * gp[2*i+1] + bp[2*i+1]);
        o[i] = (u32)lo | ((u32)hi << 16);
    }
    *(uint4*)(out + base) = make_uint4(o[0], o[1], o[2], o[3]);
}

template<bool IN16, bool RAW>
__global__ __launch_bounds__(256)
void ln_kernel(const void* __restrict__ in, u16* __restrict__ out,
               const float* __restrict__ g, const float* __restrict__ be,
               u16* __restrict__ raw_out)
{
    ln_body<IN16, RAW>(in, out, g, be, raw_out);
}

// batched pair (z = blockIdx.y); halves must touch disjoint memory
template<bool IN16, bool RAW>
__global__ __launch_bounds__(256)
void ln2_kernel(const void* __restrict__ in0, u16* __restrict__ out0, u16* __restrict__ raw0,
                const void* __restrict__ in1, u16* __restrict__ out1, u16* __restrict__ raw1,
                const float* __restrict__ g, const float* __restrict__ be)
{
    if (blockIdx.y == 0) ln_body<IN16, RAW>(in0, out0, g, be, raw0);
    else                 ln_body<IN16, RAW>(in1, out1, g, be, raw1);
}

// ---- reg-staging helper (fallback path) ----
template<bool IS16>
__device__ __forceinline__ void load_pair(const void* P, size_t off, size_t rstep,
                                          uint4& r0, uint4& r1)
{
    if constexpr (IS16) {
        const u16* p = (const u16*)P + off;
        r0 = *(const uint4*)p;
        r1 = *(const uint4*)(p + rstep);
    } else {
        const float* p = (const float*)P + off;
        float4 a0 = *(const float4*)p,           a1 = *(const float4*)(p + 4);
        float4 b0 = *(const float4*)(p + rstep), b1 = *(const float4*)(p + rstep + 4);
        r0 = pack8(a0, a1);
        r1 = pack8(b0, b1);
    }
}

// ===== FAST GEMM v3: 128x256 tile, 8 waves, gld_lds + XOR swizzle, 2-stage dbuf =====
// C[M,N] = A[M,K] @ B[N,K]^T.  Requires N multiple of 256.
// EPI: 0 plain | 1 +bias_b[row>>12][col] + skip | 2 +bias_v GELU | 3 +bias_v + skip
template<int EPI, bool OUT16>
__global__ __launch_bounds__(512)
void gemm3_kernel(const u16* __restrict__ A, const u16* __restrict__ B,
                  void* __restrict__ Cp, int N, int K,
                  const float* __restrict__ bias_b,
                  const float* __restrict__ bias_v,
                  const float* __restrict__ skip)
{
    __shared__ u16 sA[2][128 * 32];
    __shared__ u16 sB[2][256 * 32];
    const int t = threadIdx.x;
    const int w = t >> 6;
    const int lane = t & 63;
    const int lr = lane & 15;
    const int lk = lane >> 4;
    const int bm0 = blockIdx.x * 128;
    const int bn0 = blockIdx.y * 256;
    const int wrow = (w >> 2) * 64;
    const int wcol = (w & 3) * 64;

    f32x4 acc[4][4];
#pragma unroll
    for (int m = 0; m < 4; ++m)
#pragma unroll
        for (int n = 0; n < 4; ++n) acc[m][n] = (f32x4){0.f, 0.f, 0.f, 0.f};

    const int scol = ((t & 3) ^ ((t >> 3) & 3)) * 8;
    const u16* gA = A + (size_t)(bm0 + (t >> 2)) * K + scol;
    const u16* gB = B + (size_t)(bn0 + (t >> 2)) * K + scol;
    const size_t rstep = (size_t)128 * K;
    const int wo = w << 9;
    const int sa = (lk ^ ((lr >> 1) & 3)) * 8;

    GLD_LDS(gA, sA[0] + wo);
    GLD_LDS(gB, sB[0] + wo);
    GLD_LDS(gB + rstep, sB[0] + 4096 + wo);
    __syncthreads();

    int cur = 0;
    for (int kt = 32; kt <= K; kt += 32) {
        if (kt < K) {
            const int nxt = cur ^ 1;
            GLD_LDS(gA + kt, sA[nxt] + wo);
            GLD_LDS(gB + kt, sB[nxt] + wo);
            GLD_LDS(gB + kt + rstep, sB[nxt] + 4096 + wo);
        }
        bf16x8 af[4], bfr[4];
#pragma unroll
        for (int m = 0; m < 4; ++m)
            af[m] = *(const bf16x8*)&sA[cur][(wrow + m * 16 + lr) * 32 + sa];
#pragma unroll
        for (int n = 0; n < 4; ++n)
            bfr[n] = *(const bf16x8*)&sB[cur][(wcol + n * 16 + lr) * 32 + sa];
#pragma unroll
        for (int m = 0; m < 4; ++m)
#pragma unroll
            for (int n = 0; n < 4; ++n)
                acc[m][n] = __builtin_amdgcn_mfma_f32_16x16x32_bf16(af[m], bfr[n], acc[m][n], 0, 0, 0);
        if (kt < K) { __syncthreads(); cur ^= 1; }
    }

#pragma unroll
    for (int m = 0; m < 4; ++m) {
#pragma unroll
        for (int n = 0; n < 4; ++n) {
            const int col = bn0 + wcol + n * 16 + lr;
#pragma unroll
            for (int r = 0; r < 4; ++r) {
                const int row = bm0 + wrow + m * 16 + lk * 4 + r;
                const size_t idx = (size_t)row * N + col;
                float vv = acc[m][n][r];
                if (EPI == 1) vv += bias_b[(size_t)(row >> 12) * N + col] + skip[idx];
                if (EPI == 2) { vv += bias_v[col]; vv = fast_gelu(vv); }
                if (EPI == 3) vv += bias_v[col] + skip[idx];
                if (OUT16) ((u16*)Cp)[idx] = f2bf(vv);
                else       ((float*)Cp)[idx] = vv;
            }
        }
    }
}

// ===== FAST GEMM v2: 128x128 tile, 4 waves, 2-stage dbuf (W2) =====
template<int EPI, bool OUT16>
__global__ __launch_bounds__(256)
void gemm2_kernel(const u16* __restrict__ A, const u16* __restrict__ B,
                  void* __restrict__ Cp, int N, int K,
                  const float* __restrict__ bias_b,
                  const float* __restrict__ bias_v,
                  const float* __restrict__ skip)
{
    __shared__ u16 sA[2][128 * 32];
    __shared__ u16 sB[2][128 * 32];
    const int t = threadIdx.x;
    const int w = t >> 6;
    const int lane = t & 63;
    const int lr = lane & 15;
    const int lk = lane >> 4;
    const int bm0 = blockIdx.x * 128;
    const int bn0 = blockIdx.y * 128;
    const int wrow = (w >> 1) * 64;
    const int wcol = (w & 1) * 64;

    f32x4 acc[4][4];
#pragma unroll
    for (int m = 0; m < 4; ++m)
#pragma unroll
        for (int n = 0; n < 4; ++n) acc[m][n] = (f32x4){0.f, 0.f, 0.f, 0.f};

    const int scol = ((t & 3) ^ ((t >> 3) & 3)) * 8;
    const u16* gA = A + (size_t)(bm0 + (t >> 2)) * K + scol;
    const u16* gB = B + (size_t)(bn0 + (t >> 2)) * K + scol;
    const size_t rstep = (size_t)64 * K;
    const int wo = w << 9;
    const int sa = (lk ^ ((lr >> 1) & 3)) * 8;

    GLD_LDS(gA, sA[0] + wo); GLD_LDS(gA + rstep, sA[0] + wo + 2048);
    GLD_LDS(gB, sB[0] + wo); GLD_LDS(gB + rstep, sB[0] + wo + 2048);
    __syncthreads();

    int cur = 0;
    for (int kt = 32; kt <= K; kt += 32) {
        if (kt < K) {
            const int nxt = cur ^ 1;
            GLD_LDS(gA + kt, sA[nxt] + wo); GLD_LDS(gA + kt + rstep, sA[nxt] + wo + 2048);
            GLD_LDS(gB + kt, sB[nxt] + wo); GLD_LDS(gB + kt + rstep, sB[nxt] + wo + 2048);
        }
        bf16x8 af[4], bfr[4];
#pragma unroll
        for (int m = 0; m < 4; ++m)
            af[m] = *(const bf16x8*)&sA[cur][(wrow + m * 16 + lr) * 32 + sa];
#pragma unroll
        for (int n = 0; n < 4; ++n)
            bfr[n] = *(const bf16x8*)&sB[cur][(wcol + n * 16 + lr) * 32 + sa];
#pragma unroll
        for (int m = 0; m < 4; ++m)
#pragma unroll
            for (int n = 0; n < 4; ++n)
                acc[m][n] = __builtin_amdgcn_mfma_f32_16x16x32_bf16(af[m], bfr[n], acc[m][n], 0, 0, 0);
        if (kt < K) { __syncthreads(); cur ^= 1; }
    }

#pragma unroll
    for (int m = 0; m < 4; ++m) {
#pragma unroll
        for (int n = 0; n < 4; ++n) {
            const int col = bn0 + wcol + n * 16 + lr;
#pragma unroll
            for (int r = 0; r < 4; ++r) {
                const int row = bm0 + wrow + m * 16 + lk * 4 + r;
                const size_t idx = (size_t)row * N + col;
                float vv = acc[m][n][r];
                if (EPI == 1) vv += bias_b[(size_t)(row >> 12) * N + col] + skip[idx];
                if (EPI == 2) { vv += bias_v[col]; vv = fast_gelu(vv); }
                if (EPI == 3) vv += bias_v[col] + skip[idx];
                if (OUT16) ((u16*)Cp)[idx] = f2bf(vv);
                else       ((float*)Cp)[idx] = vv;
            }
        }
    }
}

// ===== FAST GEMM v3 + fused dual weighted-column-sum (no C). =====
// WM=0: w1=wa[row], w2=1-wa[row]  |  WM=1: w1=wa[row], w2=wb[row]
template<int WM>
__global__ __launch_bounds__(512)
void gemm3_red_kernel(const u16* __restrict__ A, const u16* __restrict__ B, int K,
                      const float* __restrict__ wa, const float* __restrict__ wb,
                      float* __restrict__ acc1, float* __restrict__ acc2)
{
    __shared__ u16 sA[2][128 * 32];
    __shared__ u16 sB[2][256 * 32];
    __shared__ float sred[8][2][64];
    const int t = threadIdx.x;
    const int w = t >> 6;
    const int lane = t & 63;
    const int lr = lane & 15;
    const int lk = lane >> 4;
    const int bm0 = blockIdx.x * 128;
    const int bn0 = blockIdx.y * 256;
    const int wrow = (w >> 2) * 64;
    const int wcol = (w & 3) * 64;

    f32x4 acc[4][4];
#pragma unroll
    for (int m = 0; m < 4; ++m)
#pragma unroll
        for (int n = 0; n < 4; ++n) acc[m][n] = (f32x4){0.f, 0.f, 0.f, 0.f};

    const int scol = ((t & 3) ^ ((t >> 3) & 3)) * 8;
    const u16* gA = A + (size_t)(bm0 + (t >> 2)) * K + scol;
    const u16* gB = B + (size_t)(bn0 + (t >> 2)) * K + scol;
    const size_t rstep = (size_t)128 * K;
    const int wo = w << 9;
    const int sa = (lk ^ ((lr >> 1) & 3)) * 8;

    GLD_LDS(gA, sA[0] + wo);
    GLD_LDS(gB, sB[0] + wo);
    GLD_LDS(gB + rstep, sB[0] + 4096 + wo);
    __syncthreads();

    int cur = 0;
    for (int kt = 32; kt <= K; kt += 32) {
        if (kt < K) {
            const int nxt = cur ^ 1;
            GLD_LDS(gA + kt, sA[nxt] + wo);
            GLD_LDS(gB + kt, sB[nxt] + wo);
            GLD_LDS(gB + kt + rstep, sB[nxt] + 4096 + wo);
        }
        bf16x8 af[4], bfr[4];
#pragma unroll
        for (int m = 0; m < 4; ++m)
            af[m] = *(const bf16x8*)&sA[cur][(wrow + m * 16 + lr) * 32 + sa];
#pragma unroll
        for (int n = 0; n < 4; ++n)
            bfr[n] = *(const bf16x8*)&sB[cur][(wcol + n * 16 + lr) * 32 + sa];
#pragma unroll
        for (int m = 0; m < 4; ++m)
#pragma unroll
            for (int n = 0; n < 4; ++n)
                acc[m][n] = __builtin_amdgcn_mfma_f32_16x16x32_bf16(af[m], bfr[n], acc[m][n], 0, 0, 0);
        if (kt < K) { __syncthreads(); cur ^= 1; }
    }

    float w1v[16], w2v[16];
#pragma unroll
    for (int m = 0; m < 4; ++m)
#pragma unroll
        for (int r = 0; r < 4; ++r) {
            const int row = bm0 + wrow + m * 16 + lk * 4 + r;
            if (WM == 0) { float mm = wa[row]; w1v[m*4+r] = mm; w2v[m*4+r] = 1.f - mm; }
            else         { w1v[m*4+r] = wa[row]; w2v[m*4+r] = wb[row]; }
        }
    __syncthreads();
#pragma unroll
    for (int n = 0; n < 4; ++n) {
        float s1 = 0.f, s2 = 0.f;
#pragma unroll
        for (int m = 0; m < 4; ++m)
#pragma unroll
            for (int r = 0; r < 4; ++r) {
                s1 += acc[m][n][r] * w1v[m*4+r];
                s2 += acc[m][n][r] * w2v[m*4+r];
            }
        s1 += __shfl_xor(s1, 16, 64); s1 += __shfl_xor(s1, 32, 64);
        s2 += __shfl_xor(s2, 16, 64); s2 += __shfl_xor(s2, 32, 64);
        if (lk == 0) { sred[w][0][n*16+lr] = s1; sred[w][1][n*16+lr] = s2; }
    }
    __syncthreads();
    if (t < 256) {
        const int strip = t >> 6, c = t & 63;
        const float v1 = sred[strip][0][c] + sred[strip + 4][0][c];
        const float v2 = sred[strip][1][c] + sred[strip + 4][1][c];
        const int col = bn0 + strip * 64 + c;
        const int b = bm0 >> 12;
        atomicAdd(&acc1[b * 512 + col], v1);
        atomicAdd(&acc2[b * 512 + col], v2);
    }
}

// ================= OLD reg-staged GEMM (fallback path only) =================
template<int EPI, bool A16, bool B16, bool OUT16>
__global__ __launch_bounds__(256)
void gemm_kernel(const void* __restrict__ Ap, const void* __restrict__ Wp,
                 void* __restrict__ Cp, int N, int K,
                 const float* __restrict__ bias_b,
                 const float* __restrict__ bias_v,
                 const float* __restrict__ skip)
{
    __shared__ u16 sA[128 * 32];
    __shared__ u16 sB[128 * 32];
    const int t = threadIdx.x;
    const int w = t >> 6;
    const int lane = t & 63;
    const int lr = lane & 15;
    const int lk = lane >> 4;
    const int bm0 = blockIdx.x * 128;
    const int bn0 = blockIdx.y * 128;
    const int wrow = (w >> 1) * 64;
    const int wcol = (w & 1) * 64;

    f32x4 acc[4][4];
#pragma unroll
    for (int m = 0; m < 4; ++m)
#pragma unroll
        for (int n = 0; n < 4; ++n) acc[m][n] = (f32x4){0.f, 0.f, 0.f, 0.f};

    const size_t aoff = (size_t)(bm0 + (t >> 2)) * K + (t & 3) * 8;
    const size_t boff = (size_t)(bn0 + (t >> 2)) * K + (t & 3) * 8;
    const size_t rstep = (size_t)64 * K;
    u16* dA = sA + 8 * t;
    u16* dB = sB + 8 * t;

    for (int kt = 0; kt < K; kt += 32) {
        uint4 ra0, ra1, rb0, rb1;
        load_pair<A16>(Ap, aoff + kt, rstep, ra0, ra1);
        load_pair<B16>(Wp, boff + kt, rstep, rb0, rb1);
        __syncthreads();
        *(uint4*)dA = ra0; *(uint4*)(dA + 2048) = ra1;
        *(uint4*)dB = rb0; *(uint4*)(dB + 2048) = rb1;
        __syncthreads();
        bf16x8 af[4], bfr[4];
#pragma unroll
        for (int m = 0; m < 4; ++m)
            af[m] = *(const bf16x8*)&sA[(wrow + m * 16 + lr) * 32 + lk * 8];
#pragma unroll
        for (int n = 0; n < 4; ++n)
            bfr[n] = *(const bf16x8*)&sB[(wcol + n * 16 + lr) * 32 + lk * 8];
#pragma unroll
        for (int m = 0; m < 4; ++m)
#pragma unroll
            for (int n = 0; n < 4; ++n)
                acc[m][n] = __builtin_amdgcn_mfma_f32_16x16x32_bf16(af[m], bfr[n], acc[m][n], 0, 0, 0);
    }

#pragma unroll
    for (int m = 0; m < 4; ++m) {
#pragma unroll
        for (int n = 0; n < 4; ++n) {
            const int col = bn0 + wcol + n * 16 + lr;
#pragma unroll
            for (int r = 0; r < 4; ++r) {
                const int row = bm0 + wrow + m * 16 + lk * 4 + r;
                const size_t idx = (size_t)row * N + col;
                float vv = acc[m][n][r];
                if (EPI == 1) vv += bias_b[(size_t)(row >> 12) * N + col] + skip[idx];
                if (EPI == 2) { vv += bias_v[col]; vv = fast_gelu(vv); }
                if (EPI == 3) vv += bias_v[col] + skip[idx];
                if (OUT16) ((u16*)Cp)[idx] = f2bf(vv);
                else       ((float*)Cp)[idx] = vv;
            }
        }
    }
}

template<int WM>
__global__ __launch_bounds__(256)
void gemm_red_kernel(const u16* __restrict__ A, const float* __restrict__ W, int K,
                     const float* __restrict__ wa, const float* __restrict__ wb,
                     float* __restrict__ acc1, float* __restrict__ acc2)
{
    __shared__ u16 sA[128 * 32];
    __shared__ u16 sB[128 * 32];
    __shared__ float sred[4][2][64];
    const int t = threadIdx.x;
    const int w = t >> 6;
    const int lane = t & 63;
    const int lr = lane & 15;
    const int lk = lane >> 4;
    const int bm0 = blockIdx.x * 128;
    const int bn0 = blockIdx.y * 128;
    const int wrow = (w >> 1) * 64;
    const int wcol = (w & 1) * 64;

    f32x4 acc[4][4];
#pragma unroll
    for (int m = 0; m < 4; ++m)
#pragma unroll
        for (int n = 0; n < 4; ++n) acc[m][n] = (f32x4){0.f, 0.f, 0.f, 0.f};

    const size_t aoff = (size_t)(bm0 + (t >> 2)) * K + (t & 3) * 8;
    const size_t boff = (size_t)(bn0 + (t >> 2)) * K + (t & 3) * 8;
    const size_t rstep = (size_t)64 * K;
    u16* dA = sA + 8 * t;
    u16* dB = sB + 8 * t;

    for (int kt = 0; kt < K; kt += 32) {
        uint4 ra0, ra1, rb0, rb1;
        load_pair<true >(A, aoff + kt, rstep, ra0, ra1);
        load_pair<false>(W, boff + kt, rstep, rb0, rb1);
        __syncthreads();
        *(uint4*)dA = ra0; *(uint4*)(dA + 2048) = ra1;
        *(uint4*)dB = rb0; *(uint4*)(dB + 2048) = rb1;
        __syncthreads();
        bf16x8 af[4], bfr[4];
#pragma unroll
        for (int m = 0; m < 4; ++m)
            af[m] = *(const bf16x8*)&sA[(wrow + m * 16 + lr) * 32 + lk * 8];
#pragma unroll
        for (int n = 0; n < 4; ++n)
            bfr[n] = *(const bf16x8*)&sB[(wcol + n * 16 + lr) * 32 + lk * 8];
#pragma unroll
        for (int m = 0; m < 4; ++m)
#pragma unroll
            for (int n = 0; n < 4; ++n)
                acc[m][n] = __builtin_amdgcn_mfma_f32_16x16x32_bf16(af[m], bfr[n], acc[m][n], 0, 0, 0);
    }

    float w1v[16], w2v[16];
#pragma unroll
    for (int m = 0; m < 4; ++m)
#pragma unroll
        for (int r = 0; r < 4; ++r) {
            const int row = bm0 + wrow + m * 16 + lk * 4 + r;
            if (WM == 0) { float mm = wa[row]; w1v[m*4+r] = mm; w2v[m*4+r] = 1.f - mm; }
            else         { w1v[m*4+r] = wa[row]; w2v[m*4+r] = wb[row]; }
        }
#pragma unroll
    for (int n = 0; n < 4; ++n) {
        float s1 = 0.f, s2 = 0.f;
#pragma unroll
        for (int m = 0; m < 4; ++m)
#pragma unroll
            for (int r = 0; r < 4; ++r) {
                s1 += acc[m][n][r] * w1v[m*4+r];
                s2 += acc[m][n][r] * w2v[m*4+r];
            }
        s1 += __shfl_xor(s1, 16, 64); s1 += __shfl_xor(s1, 32, 64);
        s2 += __shfl_xor(s2, 16, 64); s2 += __shfl_xor(s2, 32, 64);
        if (lk == 0) { sred[w][0][n*16+lr] = s1; sred[w][1][n*16+lr] = s2; }
    }
    __syncthreads();
    if (t < 128) {
        const int half = t >> 6, c = t & 63;
        const float v1 = sred[half][0][c] + sred[half + 2][0][c];
        const float v2 = sred[half][1][c] + sred[half + 2][1][c];
        const int col = bn0 + half * 64 + c;
        const int b = bm0 >> 12;
        atomicAdd(&acc1[b * 512 + col], v1);
        atomicAdd(&acc2[b * 512 + col], v2);
    }
}

// ---------------- per-batch row sum of f32 (b,4096) arrays ----------------
__global__ __launch_bounds__(256)
void rowsum_kernel(const float* __restrict__ in, float* __restrict__ out)
{
    __shared__ float sred[4];
    const int b = blockIdx.x, t = threadIdx.x;
    float s = 0.f;
    for (int i = 0; i < 16; ++i) s += in[b * 4096 + t + i * 256];
    s = wsum(s);
    if ((t & 63) == 0) sred[t >> 6] = s;
    __syncthreads();
    if (t == 0) out[b] = sred[0] + sred[1] + sred[2] + sred[3];
}
__global__ __launch_bounds__(256)
void rowsum2_kernel(const float* __restrict__ in0, float* __restrict__ out0,
                    const float* __restrict__ in1, float* __restrict__ out1)
{
    __shared__ float sred[4];
    const float* in = blockIdx.y ? in1 : in0;
    float* out = blockIdx.y ? out1 : out0;
    const int b = blockIdx.x, t = threadIdx.x;
    float s = 0.f;
    for (int i = 0; i < 16; ++i) s += in[b * 4096 + t + i * 256];
    s = wsum(s);
    if ((t & 63) == 0) sred[t >> 6] = s;
    __syncthreads();
    if (t == 0) out[b] = sred[0] + sred[1] + sred[2] + sred[3];
}

// ---------------- finalize fg/bg prototypes + norms ----------------
__global__ __launch_bounds__(512)
void proto_fin_kernel(const float* __restrict__ fgacc, const float* __restrict__ bgacc,
                      const float* __restrict__ denfg, float* __restrict__ fg_pro,
                      float* __restrict__ bg_pro, float* __restrict__ nfg, float* __restrict__ nbg)
{
    __shared__ float sred[16];
    const int b = blockIdx.x, c = threadIdx.x;
    const float d = denfg[b];
    const float fg = fgacc[b * 512 + c] / (d + 5e-4f);
    const float bg = bgacc[b * 512 + c] / ((4096.f - d) + 5e-4f);
    fg_pro[b * 512 + c] = fg; bg_pro[b * 512 + c] = bg;
    float s1 = wsum(fg * fg), s2 = wsum(bg * bg);
    if ((c & 63) == 0) { sred[c >> 6] = s1; sred[8 + (c >> 6)] = s2; }
    __syncthreads();
    if (c == 0) {
        float a = 0.f, bb = 0.f;
        for (int i = 0; i < 8; ++i) { a += sred[i]; bb += sred[8 + i]; }
        nfg[b] = sqrtf(a); nbg[b] = sqrtf(bb);
    }
}

// ---------------- token cosine sims -> softmax pseudo mask ----------------
__global__ __launch_bounds__(256)
void sim_kernel(const u16* __restrict__ k, const float* __restrict__ fg_pro,
                const float* __restrict__ bg_pro, const float* __restrict__ nfg,
                const float* __restrict__ nbg, float* __restrict__ pseudo_fg,
                float* __restrict__ pm)
{
    const int lane = threadIdx.x & 63;
    const int token = blockIdx.x * 4 + (threadIdx.x >> 6);
    const int b = token >> 12, n = token & 4095;
    uint4 u = *(const uint4*)(k + (size_t)token * 512 + lane * 8);
    float kv[8]; unpack8(u, kv);
    const float* fp = fg_pro + b * 512 + lane * 8;
    const float* bp = bg_pro + b * 512 + lane * 8;
    float dfg = 0.f, dbg = 0.f, kk = 0.f;
#pragma unroll
    for (int i = 0; i < 8; ++i) { dfg += kv[i] * fp[i]; dbg += kv[i] * bp[i]; kk += kv[i] * kv[i]; }
    dfg = wsum(dfg); dbg = wsum(dbg); kk = wsum(kk);
    const float nk = fmaxf(sqrtf(kk), 1e-8f);
    const float sfg = 10.f * dfg / (nk * fmaxf(nfg[b], 1e-8f));
    const float sbg = 10.f * dbg / (nk * fmaxf(nbg[b], 1e-8f));
    const float pfg = 1.f / (1.f + expf(sbg - sfg));
    if (lane == 0) {
        pseudo_fg[token] = pfg;
        pm[(size_t)b * 8192 + 4096 + n] = pfg;
        pm[(size_t)b * 8192 + n] = 1.f - pfg;
    }
}

// ---------------- pro1/pro2 mixing ----------------
__global__ __launch_bounds__(512)
void proto2_kernel(const float* __restrict__ q1acc, const float* __restrict__ q2acc,
                   const float* __restrict__ denq1, const float* __restrict__ denq2,
                   const float* __restrict__ fg_pro, const float* __restrict__ nfg,
                   float* __restrict__ pro1, float* __restrict__ pro2)
{
    __shared__ float sred[32];
    __shared__ float s1s, s2s;
    const int b = blockIdx.x, c = threadIdx.x;
    const float q1 = q1acc[b * 512 + c] / (denq1[b] + 5e-4f);
    const float q2 = q2acc[b * 512 + c] / (denq2[b] + 5e-4f);
    const float fg = fg_pro[b * 512 + c];
    float r0 = wsum(q1 * fg), r1 = wsum(q1 * q1), r2 = wsum(q2 * fg), r3 = wsum(q2 * q2);
    const int wv = c >> 6;
    if ((c & 63) == 0) { sred[wv] = r0; sred[8 + wv] = r1; sred[16 + wv] = r2; sred[24 + wv] = r3; }
    __syncthreads();
    if (c == 0) {
        float d1 = 0.f, n1 = 0.f, d2 = 0.f, n2 = 0.f;
        for (int i = 0; i < 8; ++i) { d1 += sred[i]; n1 += sred[8+i]; d2 += sred[16+i]; n2 += sred[24+i]; }
        const float nf = fmaxf(nfg[b], 1e-8f);
        s1s = (d1 / (fmaxf(sqrtf(n1), 1e-8f) * nf) + 1.f) * 0.5f;
        s2s = (d2 / (fmaxf(sqrtf(n2), 1e-8f) * nf) + 1.f) * 0.5f;
    }
    __syncthreads();
    pro1[b * 512 + c] = s1s * fg + (1.f - s1s) * q1;
    pro2[b * 512 + c] = s2s * fg + (1.f - s2s) * q2;
}

// ---------------- fold Wf@[W1;W2] -> M (512x512, bf16 out); z selects x/y ----------------
// Vectorized: block (64,4), grid (1,128,2). Thread -> 8 consecutive i outputs.
// Wf row reads are wave-uniform (scalar broadcast); W1/W2 row reads are float4 coalesced.
__global__ __launch_bounds__(256)
void mmcomb2_kernel(const float* __restrict__ Wfx, const float* __restrict__ Wx1,
                    const float* __restrict__ Wx2, u16* __restrict__ Mx,
                    const float* __restrict__ Wfy, const float* __restrict__ Wy1,
                    const float* __restrict__ Wy2, u16* __restrict__ My)
{
    const float* Wf = blockIdx.z ? Wfy : Wfx;
    const float* W1 = blockIdx.z ? Wy1 : Wx1;
    const float* W2 = blockIdx.z ? Wy2 : Wx2;
    u16* Mout = blockIdx.z ? My : Mx;
    const int o  = blockIdx.y * 4 + threadIdx.y;
    const int i0 = threadIdx.x * 8;
    const float* wfr = Wf + (size_t)o * 1024;
    float acc[8];
#pragma unroll
    for (int k = 0; k < 8; ++k) acc[k] = 0.f;
#pragma unroll 2
    for (int j = 0; j < 512; ++j) {
        const float a1 = wfr[j];
        const float a2 = wfr[512 + j];
        const float* r1 = W1 + (size_t)j * 1024 + i0;
        const float* r2 = W2 + (size_t)j * 1024 + i0;
        const float4 b10 = *(const float4*)r1, b11 = *(const float4*)(r1 + 4);
        const float4 b20 = *(const float4*)r2, b21 = *(const float4*)(r2 + 4);
        acc[0] += a1 * b10.x + a2 * b20.x;
        acc[1] += a1 * b10.y + a2 * b20.y;
        acc[2] += a1 * b10.z + a2 * b20.z;
        acc[3] += a1 * b10.w + a2 * b20.w;
        acc[4] += a1 * b11.x + a2 * b21.x;
        acc[5] += a1 * b11.y + a2 * b21.y;
        acc[6] += a1 * b11.z + a2 * b21.z;
        acc[7] += a1 * b11.w + a2 * b21.w;
    }
    const float4 lo = make_float4(acc[0], acc[1], acc[2], acc[3]);
    const float4 hi = make_float4(acc[4], acc[5], acc[6], acc[7]);
    *(uint4*)&Mout[(size_t)o * 512 + i0] = pack8(lo, hi);
}

// ---------------- batched tvec ----------------
__global__ __launch_bounds__(512)
void tvec4_kernel(const float* __restrict__ Wx1, const float* __restrict__ Wx2,
                  const float* __restrict__ Wy1, const float* __restrict__ Wy2,
                  const float* __restrict__ pro1, const float* __restrict__ pro2,
                  float* __restrict__ t1x, float* __restrict__ t2x,
                  float* __restrict__ t1y, float* __restrict__ t2y)
{
    const int z = blockIdx.z;
    const float* W = (z == 0) ? Wx1 : (z == 1) ? Wx2 : (z == 2) ? Wy1 : Wy2;
    const float* p = (z & 1) ? pro2 : pro1;
    float* tout = (z == 0) ? t1x : (z == 1) ? t2x : (z == 2) ? t1y : t2y;
    const int lane = threadIdx.x & 63;
    const int j = blockIdx.x * 8 + (threadIdx.x >> 6);
    const int b = blockIdx.y;
    const float* wr = W + (size_t)j * 1024 + 512 + lane * 8;
    const float* pr = p + b * 512 + lane * 8;
    float4 w0 = *(const float4*)wr, w1 = *(const float4*)(wr + 4);
    float4 p0 = *(const float4*)pr, p1 = *(const float4*)(pr + 4);
    float s = w0.x*p0.x + w0.y*p0.y + w0.z*p0.z + w0.w*p0.w
            + w1.x*p1.x + w1.y*p1.y + w1.z*p1.z + w1.w*p1.w;
    s = wsum(s);
    if (lane == 0) tout[b * 512 + j] = s;
}

// ---------------- batched biascomb ----------------
__global__ __launch_bounds__(512)
void biascomb2_kernel(const float* __restrict__ Wfx, const float* __restrict__ Wfy,
                      const float* __restrict__ t1x, const float* __restrict__ t2x,
                      const float* __restrict__ t1y, const float* __restrict__ t2y,
                      float* __restrict__ bias_x, float* __restrict__ bias_y)
{
    const int z = blockIdx.z;
    const float* Wf = z ? Wfy : Wfx;
    const float* t1 = z ? t1y : t1x;
    const float* t2 = z ? t2y : t2x;
    float* bias = z ? bias_y : bias_x;
    const int lane = threadIdx.x & 63;
    const int o = blockIdx.x * 8 + (threadIdx.x >> 6);
    const int b = blockIdx.y;
    const float* w1 = Wf + (size_t)o * 1024 + lane * 8;
    const float* tp1 = t1 + b * 512 + lane * 8;
    const float* tp2 = t2 + b * 512 + lane * 8;
    float s = 0.f;
#pragma unroll
    for (int h = 0; h < 2; ++h) {
        const float* wv = w1 + h * 512;
        const float* tp = h ? tp2 : tp1;
        float4 a0 = *(const float4*)wv, a1 = *(const float4*)(wv + 4);
        float4 b0 = *(const float4*)tp, b1 = *(const float4*)(tp + 4);
        s += a0.x*b0.x + a0.y*b0.y + a0.z*b0.z + a0.w*b0.w
           + a1.x*b1.x + a1.y*b1.y + a1.z*b1.z + a1.w*b1.w;
    }
    s = wsum(s);
    if (lane == 0) bias[b * 512 + o] = s;
}

extern "C" void kernel_launch(void* const* d_in, const int* in_sizes, int n_in,
                              void* d_out, int out_size, void* d_ws, size_t ws_size,
                              hipStream_t stream)
{
    const float* x   = (const float*)d_in[0];
    const float* y   = (const float*)d_in[1];
    const float* mask= (const float*)d_in[2];
    const float* pp  = (const float*)d_in[3];
    const float* g1  = (const float*)d_in[4];
    const float* be1 = (const float*)d_in[5];
    const float* g2  = (const float*)d_in[6];
    const float* be2 = (const float*)d_in[7];
    const float* Wq  = (const float*)d_in[8];
    const float* Wk  = (const float*)d_in[9];
    const float* Wv  = (const float*)d_in[10];
    const float* Wx1 = (const float*)d_in[11];
    const float* Wx2 = (const float*)d_in[12];
    const float* Wfx = (const float*)d_in[13];
    const float* Wy1 = (const float*)d_in[14];
    const float* Wy2 = (const float*)d_in[15];
    const float* Wfy = (const float*)d_in[16];
    const float* W1x = (const float*)d_in[17];
    const float* b1x = (const float*)d_in[18];
    const float* W2x = (const float*)d_in[19];
    const float* b2x = (const float*)d_in[20];
    const float* W1y = (const float*)d_in[21];
    const float* b1y = (const float*)d_in[22];
    const float* W2y = (const float*)d_in[23];
    const float* b2y = (const float*)d_in[24];

    if (ws_size < 69206016u) return;
    const bool fast = ws_size >= 78643200u;
    const bool huge = ws_size >= 145752064u;

    float* outx = (float*)d_out;
    float* outy = outx + 16777216;
    float* pmf  = outx + 33554432;

    char* wsb = (char*)d_ws;
    float* fsm = (float*)wsb;
    float* fgacc  = fsm;
    float* bgacc  = fsm + 4096;
    float* q1acc  = fsm + 8192;
    float* q2acc  = fsm + 12288;
    float* denq1  = fsm + 16384;
    float* denfg  = fsm + 16392;
    float* denq2  = fsm + 16400;
    float* nfg    = fsm + 16408;
    float* nbg    = fsm + 16416;
    float* fg_pro = fsm + 16424;
    float* bg_pro = fsm + 20520;
    float* pro1   = fsm + 24616;
    float* pro2   = fsm + 28712;
    float* t1x    = fsm + 32808;
    float* t2x    = fsm + 36904;
    float* t1y    = fsm + 41000;
    float* t2y    = fsm + 45096;
    float* bias_x = fsm + 49192;
    float* bias_y = fsm + 53288;
    float* pseudo = fsm + 57384;

    hipMemsetAsync(fsm, 0, 65568, stream);

    if (fast) {
        u16* Mx   = (u16*)(wsb + 0x60000);
        u16* My   = (u16*)(wsb + 0xE0000);
        u16* Wqb  = (u16*)(wsb + 0x160000);
        u16* Wkb  = (u16*)(wsb + 0x1E0000);
        u16* Wvb  = (u16*)(wsb + 0x260000);
        u16* W1xb = (u16*)(wsb + 0x2E0000);
        u16* W2xb = (u16*)(wsb + 0x4E0000);
        u16* W1yb = (u16*)(wsb + 0x6E0000);
        u16* W2yb = (u16*)(wsb + 0x8E0000);
        u16* WS0  = (u16*)(wsb + 0xB00000);
        u16* WS1  = WS0 + 16777216;
        u16* WS2  = WS1 + 16777216;

        u16* OX0 = (u16*)outx;               // raw x bf16
        u16* OX1 = OX0 + 16777216;           // k
        u16* OY  = (u16*)outy;               // raw y bf16, then hidden-x

        cvt3_kernel<<<dim3(128, 3), 256, 0, stream>>>(Wq, Wk, Wv, Wqb, Wkb, Wvb, 32768);
        cvt4_kernel<<<dim3(512, 4), 256, 0, stream>>>(W1x, W2x, W1y, W2y, W1xb, W2xb, W1yb, W2yb, 131072);
        mmcomb2_kernel<<<dim3(1, 128, 2), dim3(64, 4), 0, stream>>>(Wfx, Wx1, Wx2, Mx, Wfy, Wy1, Wy2, My);

        // LN1 batched (disjoint buffers): x -> WS0 (+raw OX0), y -> WS1 (+raw OY)
        ln2_kernel<false, true><<<dim3(8192, 2), 256, 0, stream>>>(x, WS0, OX0, y, WS1, OY, g1, be1);

        dim3 gq(256, 2);
        gemm3_red_kernel<0><<<gq, 512, 0, stream>>>(WS1, Wqb, 512, mask, nullptr, fgacc, bgacc);
        rowsum2_kernel<<<dim3(8, 2), 256, 0, stream>>>(mask, denfg, pp, denq2);
        proto_fin_kernel<<<8, 512, 0, stream>>>(fgacc, bgacc, denfg, fg_pro, bg_pro, nfg, nbg);

        gemm3_kernel<0, true><<<gq, 512, 0, stream>>>(WS0, Wkb, OX1, 512, 512, nullptr, nullptr, nullptr);
        sim_kernel<<<8192, 256, 0, stream>>>(OX1, fg_pro, bg_pro, nfg, nbg, pseudo, pmf);
        rowsum_kernel<<<8, 256, 0, stream>>>(pseudo, denq1);

        gemm3_red_kernel<1><<<gq, 512, 0, stream>>>(WS0, Wvb, 512, pseudo, pp, q1acc, q2acc);
        proto2_kernel<<<8, 512, 0, stream>>>(q1acc, q2acc, denq1, denq2, fg_pro, nfg, pro1, pro2);

        tvec4_kernel<<<dim3(64, 8, 4), 512, 0, stream>>>(Wx1, Wx2, Wy1, Wy2, pro1, pro2, t1x, t2x, t1y, t2y);
        biascomb2_kernel<<<dim3(64, 8, 2), 512, 0, stream>>>(Wfx, Wfy, t1x, t2x, t1y, t2y, bias_x, bias_y);

        // merges + LN2 sequential (ly lives in WS0, outside d_out)
        gemm3_kernel<1, true><<<gq, 512, 0, stream>>>(OX0, Mx, WS0, 512, 512, bias_x, nullptr, x);  // xm -> WS0
        ln_kernel<true, false><<<8192, 256, 0, stream>>>(WS0, WS1, g2, be2, nullptr);               // lx -> WS1
        gemm3_kernel<1, true><<<gq, 512, 0, stream>>>(OY, My, WS0, 512, 512, bias_y, nullptr, y);   // ym -> WS0
        ln_kernel<true, false><<<8192, 256, 0, stream>>>(WS0, WS0, g2, be2, nullptr);               // ly in-place

        // x-MLP: 2 chunks of 16384 rows, hidden in OY (raw y dead)
        for (int ch = 0; ch < 2; ++ch) {
            const size_t ro = (size_t)ch * 16384 * 512;
            gemm3_kernel<2, true><<<dim3(128, 8), 512, 0, stream>>>(WS1 + ro, W1xb, OY, 2048, 512, nullptr, b1x, nullptr);
            gemm2_kernel<3, false><<<dim3(128, 4), 256, 0, stream>>>(OY, W2xb, outx + ro, 512, 2048, nullptr, b2x, x + ro);
        }

        if (huge) {
            for (int ch = 0; ch < 2; ++ch) {
                const size_t ro = (size_t)ch * 16384 * 512;
                gemm3_kernel<2, true><<<dim3(128, 8), 512, 0, stream>>>(WS0 + ro, W1yb, WS2, 2048, 512, nullptr, b1y, nullptr);
                gemm2_kernel<3, false><<<dim3(128, 4), 256, 0, stream>>>(WS2, W2yb, outy + ro, 512, 2048, nullptr, b2y, y + ro);
            }
        } else {
            for (int ch = 0; ch < 4; ++ch) {
                const size_t ro = (size_t)ch * 8192 * 512;
                gemm3_kernel<2, true><<<dim3(64, 8), 512, 0, stream>>>(WS0 + ro, W1yb, WS1, 2048, 512, nullptr, b1y, nullptr);
                gemm2_kernel<3, false><<<dim3(64, 4), 256, 0, stream>>>(WS1, W2yb, outy + ro, 512, 2048, nullptr, b2y, y + ro);
            }
        }
    } else {
        // ---- fallback: round-4 path ----
        u16* Mx  = (u16*)(wsb + 360608);
        u16* My  = (u16*)(wsb + 884896);
        u16* WS0 = (u16*)(wsb + 2097152);
        u16* WS1 = (u16*)(wsb + 35651584);

        ln_kernel<false, false><<<8192, 256, 0, stream>>>(x, WS0, g1, be1, nullptr);
        ln_kernel<false, false><<<8192, 256, 0, stream>>>(y, WS1, g1, be1, nullptr);

        dim3 g512(256, 4);
        gemm_red_kernel<0><<<g512, 256, 0, stream>>>(WS1, Wq, 512, mask, nullptr, fgacc, bgacc);
        rowsum_kernel<<<8, 256, 0, stream>>>(mask, denfg);
        rowsum_kernel<<<8, 256, 0, stream>>>(pp, denq2);
        proto_fin_kernel<<<8, 512, 0, stream>>>(fgacc, bgacc, denfg, fg_pro, bg_pro, nfg, nbg);

        gemm_kernel<0, true, false, true><<<g512, 256, 0, stream>>>(WS0, Wk, WS1, 512, 512, nullptr, nullptr, nullptr);
        sim_kernel<<<8192, 256, 0, stream>>>(WS1, fg_pro, bg_pro, nfg, nbg, pseudo, pmf);
        rowsum_kernel<<<8, 256, 0, stream>>>(pseudo, denq1);

        gemm_red_kernel<1><<<g512, 256, 0, stream>>>(WS0, Wv, 512, pseudo, pp, q1acc, q2acc);
        proto2_kernel<<<8, 512, 0, stream>>>(q1acc, q2acc, denq1, denq2, fg_pro, nfg, pro1, pro2);

        mmcomb2_kernel<<<dim3(1, 128, 2), dim3(64, 4), 0, stream>>>(Wfx, Wx1, Wx2, Mx, Wfy, Wy1, Wy2, My);
        tvec4_kernel<<<dim3(64, 8, 4), 512, 0, stream>>>(Wx1, Wx2, Wy1, Wy2, pro1, pro2, t1x, t2x, t1y, t2y);
        biascomb2_kernel<<<dim3(64, 8, 2), 512, 0, stream>>>(Wfx, Wfy, t1x, t2x, t1y, t2y, bias_x, bias_y);

        gemm_kernel<1, false, true, true><<<g512, 256, 0, stream>>>(x, Mx, WS0, 512, 512, bias_x, nullptr, x);
        ln_kernel<true, false><<<8192, 256, 0, stream>>>(WS0, WS1, g2, be2, nullptr);
        for (int ch = 0; ch < 4; ++ch) {
            const size_t ro = (size_t)ch * 8192 * 512;
            gemm_kernel<2, true, false, true><<<dim3(64, 16), 256, 0, stream>>>(WS1 + ro, W1x, WS0, 2048, 512, nullptr, b1x, nullptr);
            gemm_kernel<3, true, false, false><<<dim3(64, 4), 256, 0, stream>>>(WS0, W2x, outx + ro, 512, 2048, nullptr, b2x, x + ro);
        }
        gemm_kernel<1, false, true, true><<<g512, 256, 0, stream>>>(y, My, WS0, 512, 512, bias_y, nullptr, y);
        ln_kernel<true, false><<<8192, 256, 0, stream>>>(WS0, WS1, g2, be2, nullptr);
        for (int ch = 0; ch < 4; ++ch) {
            const size_t ro = (size_t)ch * 8192 * 512;
            gemm_kernel<2, true, false, true><<<dim3(64, 16), 256, 0, stream>>>(WS1 + ro, W1y, WS0, 2048, 512, nullptr, b1y, nullptr);
            gemm_kernel<3, true, false, false><<<dim3(64, 4), 256, 0, stream>>>(WS0, W2y, outy + ro, 512, 2048, nullptr, b2y, y + ro);
        }
    }
    (void)in_sizes; (void)n_in; (void)out_size;
}

// Round 18
// 774.475 us; speedup vs baseline: 1.1728x; 1.1728x over previous
//
#include <hip/hip_runtime.h>
#include <stdint.h>

typedef unsigned short u16;
typedef unsigned int   u32;

typedef __attribute__((ext_vector_type(8))) __bf16 bf16x8;
typedef __attribute__((ext_vector_type(4))) float  f32x4;

#define GLD_LDS(g, l) __builtin_amdgcn_global_load_lds( \
    (__attribute__((address_space(1))) void*)(g),        \
    (__attribute__((address_space(3))) void*)(l), 16, 0, 0)

__device__ __forceinline__ float bf2f(u16 h) {
    union { u32 u; float f; } c; c.u = ((u32)h) << 16; return c.f;
}
__device__ __forceinline__ u16 f2bf(float f) {
    union { float f; u32 u; } c; c.f = f;
    return (u16)((c.u + 0x7FFFu + ((c.u >> 16) & 1u)) >> 16);
}
__device__ __forceinline__ u32 pack2(float a, float b) {
    return (u32)f2bf(a) | ((u32)f2bf(b) << 16);
}
__device__ __forceinline__ uint4 pack8(float4 a, float4 b) {
    return make_uint4(pack2(a.x, a.y), pack2(a.z, a.w), pack2(b.x, b.y), pack2(b.z, b.w));
}
__device__ __forceinline__ void unpack8(uint4 u, float v[8]) {
    v[0] = bf2f((u16)(u.x & 0xffff)); v[1] = bf2f((u16)(u.x >> 16));
    v[2] = bf2f((u16)(u.y & 0xffff)); v[3] = bf2f((u16)(u.y >> 16));
    v[4] = bf2f((u16)(u.z & 0xffff)); v[5] = bf2f((u16)(u.z >> 16));
    v[6] = bf2f((u16)(u.w & 0xffff)); v[7] = bf2f((u16)(u.w >> 16));
}
__device__ __forceinline__ float wsum(float v) {
#pragma unroll
    for (int o = 32; o > 0; o >>= 1) v += __shfl_xor(v, o, 64);
    return v;
}
// fast tanh-form GELU: max abs err ~3e-3 (<< tolerance), saturates correctly
__device__ __forceinline__ float fast_gelu(float x) {
    const float u = x * (1.f + 0.044715f * x * x);
    return x / (1.f + __expf(-1.5957691216f * u));
}

// ---------------- f32 -> bf16 convert, batched over z ----------------
__global__ __launch_bounds__(256)
void cvt4_kernel(const float* __restrict__ a, const float* __restrict__ b,
                 const float* __restrict__ c, const float* __restrict__ d,
                 u16* __restrict__ oa, u16* __restrict__ ob,
                 u16* __restrict__ oc, u16* __restrict__ od, int n8)
{
    const int i = blockIdx.x * 256 + threadIdx.x;
    if (i >= n8) return;
    const int z = blockIdx.y;
    const float* in = (z == 0) ? a : (z == 1) ? b : (z == 2) ? c : d;
    u16* out = (z == 0) ? oa : (z == 1) ? ob : (z == 2) ? oc : od;
    const float* p = in + (size_t)i * 8;
    float4 u = *(const float4*)p, v = *(const float4*)(p + 4);
    *(uint4*)(out + (size_t)i * 8) = pack8(u, v);
}
__global__ __launch_bounds__(256)
void cvt3_kernel(const float* __restrict__ a, const float* __restrict__ b,
                 const float* __restrict__ c,
                 u16* __restrict__ oa, u16* __restrict__ ob, u16* __restrict__ oc, int n8)
{
    const int i = blockIdx.x * 256 + threadIdx.x;
    if (i >= n8) return;
    const int z = blockIdx.y;
    const float* in = (z == 0) ? a : (z == 1) ? b : c;
    u16* out = (z == 0) ? oa : (z == 1) ? ob : oc;
    const float* p = in + (size_t)i * 8;
    float4 u = *(const float4*)p, v = *(const float4*)(p + 4);
    *(uint4*)(out + (size_t)i * 8) = pack8(u, v);
}
__global__ __launch_bounds__(256)
void cvt2_kernel(const float* __restrict__ a, const float* __restrict__ b,
                 u16* __restrict__ oa, u16* __restrict__ ob, int n8)
{
    const int i = blockIdx.x * 256 + threadIdx.x;
    if (i >= n8) return;
    const float* in = blockIdx.y ? b : a;
    u16* out = blockIdx.y ? ob : oa;
    const float* p = in + (size_t)i * 8;
    float4 u = *(const float4*)p, v = *(const float4*)(p + 4);
    *(uint4*)(out + (size_t)i * 8) = pack8(u, v);
}

// ---------------- transpose first-half columns of W (512x1024 f32) -> bf16 Wt[i][j] ----------------
// z: 0 Wx1->Wtx[:, :512], 1 Wx2->Wtx[:, 512:], 2 Wy1->Wty[:, :512], 3 Wy2->Wty[:, 512:]
__global__ __launch_bounds__(256)
void wtrans_kernel(const float* __restrict__ W1x, const float* __restrict__ W2x,
                   const float* __restrict__ W1y, const float* __restrict__ W2y,
                   u16* __restrict__ Wtx, u16* __restrict__ Wty)
{
    __shared__ float tile[32][33];
    const int z = blockIdx.z;
    const float* src = (z == 0) ? W1x : (z == 1) ? W2x : (z == 2) ? W1y : W2y;
    u16* dst = (z < 2) ? Wtx : Wty;
    const int joff = (z & 1) * 512;
    const int j0 = blockIdx.y * 32;   // source row block (j)
    const int i0 = blockIdx.x * 32;   // source col block (i < 512)
    for (int r = threadIdx.y; r < 32; r += 8)
        tile[r][threadIdx.x] = src[(size_t)(j0 + r) * 1024 + i0 + threadIdx.x];
    __syncthreads();
    for (int r = threadIdx.y; r < 32; r += 8)
        dst[(size_t)(i0 + r) * 1024 + joff + j0 + threadIdx.x] = f2bf(tile[threadIdx.x][r]);
}

// ---------------- LayerNorm core ----------------
template<bool IN16, bool RAW>
__device__ __forceinline__ void ln_body(const void* in, u16* out,
                                        const float* g, const float* be, u16* raw_out)
{
    const int lane = threadIdx.x & 63;
    const size_t row = (size_t)blockIdx.x * 4 + (threadIdx.x >> 6);
    const size_t base = row * 512 + lane * 8;
    float v[8];
    if constexpr (IN16) {
        unpack8(*(const uint4*)((const u16*)in + base), v);
    } else {
        const float* p = (const float*)in + base;
        float4 a = *(const float4*)p, b = *(const float4*)(p + 4);
        v[0]=a.x; v[1]=a.y; v[2]=a.z; v[3]=a.w; v[4]=b.x; v[5]=b.y; v[6]=b.z; v[7]=b.w;
    }
    if constexpr (RAW) {
        u32 ro[4];
#pragma unroll
        for (int i = 0; i < 4; ++i) ro[i] = pack2(v[2*i], v[2*i+1]);
        *(uint4*)(raw_out + base) = make_uint4(ro[0], ro[1], ro[2], ro[3]);
    }
    float s = 0.f, ss = 0.f;
#pragma unroll
    for (int i = 0; i < 8; ++i) { s += v[i]; ss += v[i] * v[i]; }
    s = wsum(s); ss = wsum(ss);
    const float mean = s * (1.f / 512.f);
    const float rstd = rsqrtf(ss * (1.f / 512.f) - mean * mean + 1e-5f);
    const float* gp = g + lane * 8;
    const float* bp = be + lane * 8;
    u32 o[4];
#pragma unroll
    for (int i = 0; i < 4; ++i) {
        u16 lo = f2bf((v[2*i]   - mean) * rstd * gp[2*i]   + bp[2*i]);
        u16 hi = f2bf((v[2*i+1] - mean) * rstd * gp[2*i+1] + bp[2*i+1]);
        o[i] = (u32)lo | ((u32)hi << 16);
    }
    *(uint4*)(out + base) = make_uint4(o[0], o[1], o[2], o[3]);
}

template<bool IN16, bool RAW>
__global__ __launch_bounds__(256)
void ln_kernel(const void* __restrict__ in, u16* __restrict__ out,
               const float* __restrict__ g, const float* __restrict__ be,
               u16* __restrict__ raw_out)
{
    ln_body<IN16, RAW>(in, out, g, be, raw_out);
}

// batched pair (z = blockIdx.y); halves must touch disjoint memory
template<bool IN16, bool RAW>
__global__ __launch_bounds__(256)
void ln2_kernel(const void* __restrict__ in0, u16* __restrict__ out0, u16* __restrict__ raw0,
                const void* __restrict__ in1, u16* __restrict__ out1, u16* __restrict__ raw1,
                const float* __restrict__ g, const float* __restrict__ be)
{
    if (blockIdx.y == 0) ln_body<IN16, RAW>(in0, out0, g, be, raw0);
    else                 ln_body<IN16, RAW>(in1, out1, g, be, raw1);
}

// ---- reg-staging helper (fallback path) ----
template<bool IS16>
__device__ __forceinline__ void load_pair(const void* P, size_t off, size_t rstep,
                                          uint4& r0, uint4& r1)
{
    if constexpr (IS16) {
        const u16* p = (const u16*)P + off;
        r0 = *(const uint4*)p;
        r1 = *(const uint4*)(p + rstep);
    } else {
        const float* p = (const float*)P + off;
        float4 a0 = *(const float4*)p,           a1 = *(const float4*)(p + 4);
        float4 b0 = *(const float4*)(p + rstep), b1 = *(const float4*)(p + rstep + 4);
        r0 = pack8(a0, a1);
        r1 = pack8(b0, b1);
    }
}

// ===== FAST GEMM v3: 128x256 tile, 8 waves, gld_lds + XOR swizzle, 2-stage dbuf =====
// C[M,N] = A[M,K] @ B[N,K]^T.  Requires N multiple of 256.
// EPI: 0 plain | 1 +bias_b[row>>12][col] + skip | 2 +bias_v GELU | 3 +bias_v + skip
template<int EPI, bool OUT16>
__global__ __launch_bounds__(512)
void gemm3_kernel(const u16* __restrict__ A, const u16* __restrict__ B,
                  void* __restrict__ Cp, int N, int K,
                  const float* __restrict__ bias_b,
                  const float* __restrict__ bias_v,
                  const float* __restrict__ skip)
{
    __shared__ u16 sA[2][128 * 32];
    __shared__ u16 sB[2][256 * 32];
    const int t = threadIdx.x;
    const int w = t >> 6;
    const int lane = t & 63;
    const int lr = lane & 15;
    const int lk = lane >> 4;
    const int bm0 = blockIdx.x * 128;
    const int bn0 = blockIdx.y * 256;
    const int wrow = (w >> 2) * 64;
    const int wcol = (w & 3) * 64;

    f32x4 acc[4][4];
#pragma unroll
    for (int m = 0; m < 4; ++m)
#pragma unroll
        for (int n = 0; n < 4; ++n) acc[m][n] = (f32x4){0.f, 0.f, 0.f, 0.f};

    const int scol = ((t & 3) ^ ((t >> 3) & 3)) * 8;
    const u16* gA = A + (size_t)(bm0 + (t >> 2)) * K + scol;
    const u16* gB = B + (size_t)(bn0 + (t >> 2)) * K + scol;
    const size_t rstep = (size_t)128 * K;
    const int wo = w << 9;
    const int sa = (lk ^ ((lr >> 1) & 3)) * 8;

    GLD_LDS(gA, sA[0] + wo);
    GLD_LDS(gB, sB[0] + wo);
    GLD_LDS(gB + rstep, sB[0] + 4096 + wo);
    __syncthreads();

    int cur = 0;
    for (int kt = 32; kt <= K; kt += 32) {
        if (kt < K) {
            const int nxt = cur ^ 1;
            GLD_LDS(gA + kt, sA[nxt] + wo);
            GLD_LDS(gB + kt, sB[nxt] + wo);
            GLD_LDS(gB + kt + rstep, sB[nxt] + 4096 + wo);
        }
        bf16x8 af[4], bfr[4];
#pragma unroll
        for (int m = 0; m < 4; ++m)
            af[m] = *(const bf16x8*)&sA[cur][(wrow + m * 16 + lr) * 32 + sa];
#pragma unroll
        for (int n = 0; n < 4; ++n)
            bfr[n] = *(const bf16x8*)&sB[cur][(wcol + n * 16 + lr) * 32 + sa];
#pragma unroll
        for (int m = 0; m < 4; ++m)
#pragma unroll
            for (int n = 0; n < 4; ++n)
                acc[m][n] = __builtin_amdgcn_mfma_f32_16x16x32_bf16(af[m], bfr[n], acc[m][n], 0, 0, 0);
        if (kt < K) { __syncthreads(); cur ^= 1; }
    }

#pragma unroll
    for (int m = 0; m < 4; ++m) {
#pragma unroll
        for (int n = 0; n < 4; ++n) {
            const int col = bn0 + wcol + n * 16 + lr;
#pragma unroll
            for (int r = 0; r < 4; ++r) {
                const int row = bm0 + wrow + m * 16 + lk * 4 + r;
                const size_t idx = (size_t)row * N + col;
                float vv = acc[m][n][r];
                if (EPI == 1) vv += bias_b[(size_t)(row >> 12) * N + col] + skip[idx];
                if (EPI == 2) { vv += bias_v[col]; vv = fast_gelu(vv); }
                if (EPI == 3) vv += bias_v[col] + skip[idx];
                if (OUT16) ((u16*)Cp)[idx] = f2bf(vv);
                else       ((float*)Cp)[idx] = vv;
            }
        }
    }
}

// ===== FAST GEMM v2: 128x128 tile, 4 waves, 2-stage dbuf (W2, M-fold) =====
template<int EPI, bool OUT16>
__global__ __launch_bounds__(256)
void gemm2_kernel(const u16* __restrict__ A, const u16* __restrict__ B,
                  void* __restrict__ Cp, int N, int K,
                  const float* __restrict__ bias_b,
                  const float* __restrict__ bias_v,
                  const float* __restrict__ skip)
{
    __shared__ u16 sA[2][128 * 32];
    __shared__ u16 sB[2][128 * 32];
    const int t = threadIdx.x;
    const int w = t >> 6;
    const int lane = t & 63;
    const int lr = lane & 15;
    const int lk = lane >> 4;
    const int bm0 = blockIdx.x * 128;
    const int bn0 = blockIdx.y * 128;
    const int wrow = (w >> 1) * 64;
    const int wcol = (w & 1) * 64;

    f32x4 acc[4][4];
#pragma unroll
    for (int m = 0; m < 4; ++m)
#pragma unroll
        for (int n = 0; n < 4; ++n) acc[m][n] = (f32x4){0.f, 0.f, 0.f, 0.f};

    const int scol = ((t & 3) ^ ((t >> 3) & 3)) * 8;
    const u16* gA = A + (size_t)(bm0 + (t >> 2)) * K + scol;
    const u16* gB = B + (size_t)(bn0 + (t >> 2)) * K + scol;
    const size_t rstep = (size_t)64 * K;
    const int wo = w << 9;
    const int sa = (lk ^ ((lr >> 1) & 3)) * 8;

    GLD_LDS(gA, sA[0] + wo); GLD_LDS(gA + rstep, sA[0] + wo + 2048);
    GLD_LDS(gB, sB[0] + wo); GLD_LDS(gB + rstep, sB[0] + wo + 2048);
    __syncthreads();

    int cur = 0;
    for (int kt = 32; kt <= K; kt += 32) {
        if (kt < K) {
            const int nxt = cur ^ 1;
            GLD_LDS(gA + kt, sA[nxt] + wo); GLD_LDS(gA + kt + rstep, sA[nxt] + wo + 2048);
            GLD_LDS(gB + kt, sB[nxt] + wo); GLD_LDS(gB + kt + rstep, sB[nxt] + wo + 2048);
        }
        bf16x8 af[4], bfr[4];
#pragma unroll
        for (int m = 0; m < 4; ++m)
            af[m] = *(const bf16x8*)&sA[cur][(wrow + m * 16 + lr) * 32 + sa];
#pragma unroll
        for (int n = 0; n < 4; ++n)
            bfr[n] = *(const bf16x8*)&sB[cur][(wcol + n * 16 + lr) * 32 + sa];
#pragma unroll
        for (int m = 0; m < 4; ++m)
#pragma unroll
            for (int n = 0; n < 4; ++n)
                acc[m][n] = __builtin_amdgcn_mfma_f32_16x16x32_bf16(af[m], bfr[n], acc[m][n], 0, 0, 0);
        if (kt < K) { __syncthreads(); cur ^= 1; }
    }

#pragma unroll
    for (int m = 0; m < 4; ++m) {
#pragma unroll
        for (int n = 0; n < 4; ++n) {
            const int col = bn0 + wcol + n * 16 + lr;
#pragma unroll
            for (int r = 0; r < 4; ++r) {
                const int row = bm0 + wrow + m * 16 + lk * 4 + r;
                const size_t idx = (size_t)row * N + col;
                float vv = acc[m][n][r];
                if (EPI == 1) vv += bias_b[(size_t)(row >> 12) * N + col] + skip[idx];
                if (EPI == 2) { vv += bias_v[col]; vv = fast_gelu(vv); }
                if (EPI == 3) vv += bias_v[col] + skip[idx];
                if (OUT16) ((u16*)Cp)[idx] = f2bf(vv);
                else       ((float*)Cp)[idx] = vv;
            }
        }
    }
}

// z-batched pair of gemm2 (disjoint buffers only). bias_b unused.
template<int EPI, bool OUT16>
__global__ __launch_bounds__(256)
void gemm2z_kernel(const u16* __restrict__ A0, const u16* __restrict__ B0, void* __restrict__ C0,
                   const float* __restrict__ bv0, const float* __restrict__ sk0,
                   const u16* __restrict__ A1, const u16* __restrict__ B1, void* __restrict__ C1,
                   const float* __restrict__ bv1, const float* __restrict__ sk1,
                   int N, int K)
{
    __shared__ u16 sA[2][128 * 32];
    __shared__ u16 sB[2][128 * 32];
    const u16* A = blockIdx.z ? A1 : A0;
    const u16* B = blockIdx.z ? B1 : B0;
    void* Cp = blockIdx.z ? C1 : C0;
    const float* bias_v = blockIdx.z ? bv1 : bv0;
    const float* skip = blockIdx.z ? sk1 : sk0;
    const int t = threadIdx.x;
    const int w = t >> 6;
    const int lane = t & 63;
    const int lr = lane & 15;
    const int lk = lane >> 4;
    const int bm0 = blockIdx.x * 128;
    const int bn0 = blockIdx.y * 128;
    const int wrow = (w >> 1) * 64;
    const int wcol = (w & 1) * 64;

    f32x4 acc[4][4];
#pragma unroll
    for (int m = 0; m < 4; ++m)
#pragma unroll
        for (int n = 0; n < 4; ++n) acc[m][n] = (f32x4){0.f, 0.f, 0.f, 0.f};

    const int scol = ((t & 3) ^ ((t >> 3) & 3)) * 8;
    const u16* gA = A + (size_t)(bm0 + (t >> 2)) * K + scol;
    const u16* gB = B + (size_t)(bn0 + (t >> 2)) * K + scol;
    const size_t rstep = (size_t)64 * K;
    const int wo = w << 9;
    const int sa = (lk ^ ((lr >> 1) & 3)) * 8;

    GLD_LDS(gA, sA[0] + wo); GLD_LDS(gA + rstep, sA[0] + wo + 2048);
    GLD_LDS(gB, sB[0] + wo); GLD_LDS(gB + rstep, sB[0] + wo + 2048);
    __syncthreads();

    int cur = 0;
    for (int kt = 32; kt <= K; kt += 32) {
        if (kt < K) {
            const int nxt = cur ^ 1;
            GLD_LDS(gA + kt, sA[nxt] + wo); GLD_LDS(gA + kt + rstep, sA[nxt] + wo + 2048);
            GLD_LDS(gB + kt, sB[nxt] + wo); GLD_LDS(gB + kt + rstep, sB[nxt] + wo + 2048);
        }
        bf16x8 af[4], bfr[4];
#pragma unroll
        for (int m = 0; m < 4; ++m)
            af[m] = *(const bf16x8*)&sA[cur][(wrow + m * 16 + lr) * 32 + sa];
#pragma unroll
        for (int n = 0; n < 4; ++n)
            bfr[n] = *(const bf16x8*)&sB[cur][(wcol + n * 16 + lr) * 32 + sa];
#pragma unroll
        for (int m = 0; m < 4; ++m)
#pragma unroll
            for (int n = 0; n < 4; ++n)
                acc[m][n] = __builtin_amdgcn_mfma_f32_16x16x32_bf16(af[m], bfr[n], acc[m][n], 0, 0, 0);
        if (kt < K) { __syncthreads(); cur ^= 1; }
    }

#pragma unroll
    for (int m = 0; m < 4; ++m) {
#pragma unroll
        for (int n = 0; n < 4; ++n) {
            const int col = bn0 + wcol + n * 16 + lr;
#pragma unroll
            for (int r = 0; r < 4; ++r) {
                const int row = bm0 + wrow + m * 16 + lk * 4 + r;
                const size_t idx = (size_t)row * N + col;
                float vv = acc[m][n][r];
                if (EPI == 2) { vv += bias_v[col]; vv = fast_gelu(vv); }
                if (EPI == 3) vv += bias_v[col] + skip[idx];
                if (OUT16) ((u16*)Cp)[idx] = f2bf(vv);
                else       ((float*)Cp)[idx] = vv;
            }
        }
    }
}

// ===== FAST GEMM v3 + fused dual weighted-column-sum (no C). =====
// WM=0: w1=wa[row], w2=1-wa[row]  |  WM=1: w1=wa[row], w2=wb[row]
template<int WM>
__global__ __launch_bounds__(512)
void gemm3_red_kernel(const u16* __restrict__ A, const u16* __restrict__ B, int K,
                      const float* __restrict__ wa, const float* __restrict__ wb,
                      float* __restrict__ acc1, float* __restrict__ acc2)
{
    __shared__ u16 sA[2][128 * 32];
    __shared__ u16 sB[2][256 * 32];
    __shared__ float sred[8][2][64];
    const int t = threadIdx.x;
    const int w = t >> 6;
    const int lane = t & 63;
    const int lr = lane & 15;
    const int lk = lane >> 4;
    const int bm0 = blockIdx.x * 128;
    const int bn0 = blockIdx.y * 256;
    const int wrow = (w >> 2) * 64;
    const int wcol = (w & 3) * 64;

    f32x4 acc[4][4];
#pragma unroll
    for (int m = 0; m < 4; ++m)
#pragma unroll
        for (int n = 0; n < 4; ++n) acc[m][n] = (f32x4){0.f, 0.f, 0.f, 0.f};

    const int scol = ((t & 3) ^ ((t >> 3) & 3)) * 8;
    const u16* gA = A + (size_t)(bm0 + (t >> 2)) * K + scol;
    const u16* gB = B + (size_t)(bn0 + (t >> 2)) * K + scol;
    const size_t rstep = (size_t)128 * K;
    const int wo = w << 9;
    const int sa = (lk ^ ((lr >> 1) & 3)) * 8;

    GLD_LDS(gA, sA[0] + wo);
    GLD_LDS(gB, sB[0] + wo);
    GLD_LDS(gB + rstep, sB[0] + 4096 + wo);
    __syncthreads();

    int cur = 0;
    for (int kt = 32; kt <= K; kt += 32) {
        if (kt < K) {
            const int nxt = cur ^ 1;
            GLD_LDS(gA + kt, sA[nxt] + wo);
            GLD_LDS(gB + kt, sB[nxt] + wo);
            GLD_LDS(gB + kt + rstep, sB[nxt] + 4096 + wo);
        }
        bf16x8 af[4], bfr[4];
#pragma unroll
        for (int m = 0; m < 4; ++m)
            af[m] = *(const bf16x8*)&sA[cur][(wrow + m * 16 + lr) * 32 + sa];
#pragma unroll
        for (int n = 0; n < 4; ++n)
            bfr[n] = *(const bf16x8*)&sB[cur][(wcol + n * 16 + lr) * 32 + sa];
#pragma unroll
        for (int m = 0; m < 4; ++m)
#pragma unroll
            for (int n = 0; n < 4; ++n)
                acc[m][n] = __builtin_amdgcn_mfma_f32_16x16x32_bf16(af[m], bfr[n], acc[m][n], 0, 0, 0);
        if (kt < K) { __syncthreads(); cur ^= 1; }
    }

    float w1v[16], w2v[16];
#pragma unroll
    for (int m = 0; m < 4; ++m)
#pragma unroll
        for (int r = 0; r < 4; ++r) {
            const int row = bm0 + wrow + m * 16 + lk * 4 + r;
            if (WM == 0) { float mm = wa[row]; w1v[m*4+r] = mm; w2v[m*4+r] = 1.f - mm; }
            else         { w1v[m*4+r] = wa[row]; w2v[m*4+r] = wb[row]; }
        }
    __syncthreads();
#pragma unroll
    for (int n = 0; n < 4; ++n) {
        float s1 = 0.f, s2 = 0.f;
#pragma unroll
        for (int m = 0; m < 4; ++m)
#pragma unroll
            for (int r = 0; r < 4; ++r) {
                s1 += acc[m][n][r] * w1v[m*4+r];
                s2 += acc[m][n][r] * w2v[m*4+r];
            }
        s1 += __shfl_xor(s1, 16, 64); s1 += __shfl_xor(s1, 32, 64);
        s2 += __shfl_xor(s2, 16, 64); s2 += __shfl_xor(s2, 32, 64);
        if (lk == 0) { sred[w][0][n*16+lr] = s1; sred[w][1][n*16+lr] = s2; }
    }
    __syncthreads();
    if (t < 256) {
        const int strip = t >> 6, c = t & 63;
        const float v1 = sred[strip][0][c] + sred[strip + 4][0][c];
        const float v2 = sred[strip][1][c] + sred[strip + 4][1][c];
        const int col = bn0 + strip * 64 + c;
        const int b = bm0 >> 12;
        atomicAdd(&acc1[b * 512 + col], v1);
        atomicAdd(&acc2[b * 512 + col], v2);
    }
}

// ================= OLD reg-staged GEMM (fallback path only) =================
template<int EPI, bool A16, bool B16, bool OUT16>
__global__ __launch_bounds__(256)
void gemm_kernel(const void* __restrict__ Ap, const void* __restrict__ Wp,
                 void* __restrict__ Cp, int N, int K,
                 const float* __restrict__ bias_b,
                 const float* __restrict__ bias_v,
                 const float* __restrict__ skip)
{
    __shared__ u16 sA[128 * 32];
    __shared__ u16 sB[128 * 32];
    const int t = threadIdx.x;
    const int w = t >> 6;
    const int lane = t & 63;
    const int lr = lane & 15;
    const int lk = lane >> 4;
    const int bm0 = blockIdx.x * 128;
    const int bn0 = blockIdx.y * 128;
    const int wrow = (w >> 1) * 64;
    const int wcol = (w & 1) * 64;

    f32x4 acc[4][4];
#pragma unroll
    for (int m = 0; m < 4; ++m)
#pragma unroll
        for (int n = 0; n < 4; ++n) acc[m][n] = (f32x4){0.f, 0.f, 0.f, 0.f};

    const size_t aoff = (size_t)(bm0 + (t >> 2)) * K + (t & 3) * 8;
    const size_t boff = (size_t)(bn0 + (t >> 2)) * K + (t & 3) * 8;
    const size_t rstep = (size_t)64 * K;
    u16* dA = sA + 8 * t;
    u16* dB = sB + 8 * t;

    for (int kt = 0; kt < K; kt += 32) {
        uint4 ra0, ra1, rb0, rb1;
        load_pair<A16>(Ap, aoff + kt, rstep, ra0, ra1);
        load_pair<B16>(Wp, boff + kt, rstep, rb0, rb1);
        __syncthreads();
        *(uint4*)dA = ra0; *(uint4*)(dA + 2048) = ra1;
        *(uint4*)dB = rb0; *(uint4*)(dB + 2048) = rb1;
        __syncthreads();
        bf16x8 af[4], bfr[4];
#pragma unroll
        for (int m = 0; m < 4; ++m)
            af[m] = *(const bf16x8*)&sA[(wrow + m * 16 + lr) * 32 + lk * 8];
#pragma unroll
        for (int n = 0; n < 4; ++n)
            bfr[n] = *(const bf16x8*)&sB[(wcol + n * 16 + lr) * 32 + lk * 8];
#pragma unroll
        for (int m = 0; m < 4; ++m)
#pragma unroll
            for (int n = 0; n < 4; ++n)
                acc[m][n] = __builtin_amdgcn_mfma_f32_16x16x32_bf16(af[m], bfr[n], acc[m][n], 0, 0, 0);
    }

#pragma unroll
    for (int m = 0; m < 4; ++m) {
#pragma unroll
        for (int n = 0; n < 4; ++n) {
            const int col = bn0 + wcol + n * 16 + lr;
#pragma unroll
            for (int r = 0; r < 4; ++r) {
                const int row = bm0 + wrow + m * 16 + lk * 4 + r;
                const size_t idx = (size_t)row * N + col;
                float vv = acc[m][n][r];
                if (EPI == 1) vv += bias_b[(size_t)(row >> 12) * N + col] + skip[idx];
                if (EPI == 2) { vv += bias_v[col]; vv = fast_gelu(vv); }
                if (EPI == 3) vv += bias_v[col] + skip[idx];
                if (OUT16) ((u16*)Cp)[idx] = f2bf(vv);
                else       ((float*)Cp)[idx] = vv;
            }
        }
    }
}

template<int WM>
__global__ __launch_bounds__(256)
void gemm_red_kernel(const u16* __restrict__ A, const float* __restrict__ W, int K,
                     const float* __restrict__ wa, const float* __restrict__ wb,
                     float* __restrict__ acc1, float* __restrict__ acc2)
{
    __shared__ u16 sA[128 * 32];
    __shared__ u16 sB[128 * 32];
    __shared__ float sred[4][2][64];
    const int t = threadIdx.x;
    const int w = t >> 6;
    const int lane = t & 63;
    const int lr = lane & 15;
    const int lk = lane >> 4;
    const int bm0 = blockIdx.x * 128;
    const int bn0 = blockIdx.y * 128;
    const int wrow = (w >> 1) * 64;
    const int wcol = (w & 1) * 64;

    f32x4 acc[4][4];
#pragma unroll
    for (int m = 0; m < 4; ++m)
#pragma unroll
        for (int n = 0; n < 4; ++n) acc[m][n] = (f32x4){0.f, 0.f, 0.f, 0.f};

    const size_t aoff = (size_t)(bm0 + (t >> 2)) * K + (t & 3) * 8;
    const size_t boff = (size_t)(bn0 + (t >> 2)) * K + (t & 3) * 8;
    const size_t rstep = (size_t)64 * K;
    u16* dA = sA + 8 * t;
    u16* dB = sB + 8 * t;

    for (int kt = 0; kt < K; kt += 32) {
        uint4 ra0, ra1, rb0, rb1;
        load_pair<true >(A, aoff + kt, rstep, ra0, ra1);
        load_pair<false>(W, boff + kt, rstep, rb0, rb1);
        __syncthreads();
        *(uint4*)dA = ra0; *(uint4*)(dA + 2048) = ra1;
        *(uint4*)dB = rb0; *(uint4*)(dB + 2048) = rb1;
        __syncthreads();
        bf16x8 af[4], bfr[4];
#pragma unroll
        for (int m = 0; m < 4; ++m)
            af[m] = *(const bf16x8*)&sA[(wrow + m * 16 + lr) * 32 + lk * 8];
#pragma unroll
        for (int n = 0; n < 4; ++n)
            bfr[n] = *(const bf16x8*)&sB[(wcol + n * 16 + lr) * 32 + lk * 8];
#pragma unroll
        for (int m = 0; m < 4; ++m)
#pragma unroll
            for (int n = 0; n < 4; ++n)
                acc[m][n] = __builtin_amdgcn_mfma_f32_16x16x32_bf16(af[m], bfr[n], acc[m][n], 0, 0, 0);
    }

    float w1v[16], w2v[16];
#pragma unroll
    for (int m = 0; m < 4; ++m)
#pragma unroll
        for (int r = 0; r < 4; ++r) {
            const int row = bm0 + wrow + m * 16 + lk * 4 + r;
            if (WM == 0) { float mm = wa[row]; w1v[m*4+r] = mm; w2v[m*4+r] = 1.f - mm; }
            else         { w1v[m*4+r] = wa[row]; w2v[m*4+r] = wb[row]; }
        }
#pragma unroll
    for (int n = 0; n < 4; ++n) {
        float s1 = 0.f, s2 = 0.f;
#pragma unroll
        for (int m = 0; m < 4; ++m)
#pragma unroll
            for (int r = 0; r < 4; ++r) {
                s1 += acc[m][n][r] * w1v[m*4+r];
                s2 += acc[m][n][r] * w2v[m*4+r];
            }
        s1 += __shfl_xor(s1, 16, 64); s1 += __shfl_xor(s1, 32, 64);
        s2 += __shfl_xor(s2, 16, 64); s2 += __shfl_xor(s2, 32, 64);
        if (lk == 0) { sred[w][0][n*16+lr] = s1; sred[w][1][n*16+lr] = s2; }
    }
    __syncthreads();
    if (t < 128) {
        const int half = t >> 6, c = t & 63;
        const float v1 = sred[half][0][c] + sred[half + 2][0][c];
        const float v2 = sred[half][1][c] + sred[half + 2][1][c];
        const int col = bn0 + half * 64 + c;
        const int b = bm0 >> 12;
        atomicAdd(&acc1[b * 512 + col], v1);
        atomicAdd(&acc2[b * 512 + col], v2);
    }
}

// ---------------- per-batch row sum of f32 (b,4096) arrays ----------------
__global__ __launch_bounds__(256)
void rowsum_kernel(const float* __restrict__ in, float* __restrict__ out)
{
    __shared__ float sred[4];
    const int b = blockIdx.x, t = threadIdx.x;
    float s = 0.f;
    for (int i = 0; i < 16; ++i) s += in[b * 4096 + t + i * 256];
    s = wsum(s);
    if ((t & 63) == 0) sred[t >> 6] = s;
    __syncthreads();
    if (t == 0) out[b] = sred[0] + sred[1] + sred[2] + sred[3];
}
__global__ __launch_bounds__(256)
void rowsum2_kernel(const float* __restrict__ in0, float* __restrict__ out0,
                    const float* __restrict__ in1, float* __restrict__ out1)
{
    __shared__ float sred[4];
    const float* in = blockIdx.y ? in1 : in0;
    float* out = blockIdx.y ? out1 : out0;
    const int b = blockIdx.x, t = threadIdx.x;
    float s = 0.f;
    for (int i = 0; i < 16; ++i) s += in[b * 4096 + t + i * 256];
    s = wsum(s);
    if ((t & 63) == 0) sred[t >> 6] = s;
    __syncthreads();
    if (t == 0) out[b] = sred[0] + sred[1] + sred[2] + sred[3];
}

// ---------------- finalize fg/bg prototypes + norms ----------------
__global__ __launch_bounds__(512)
void proto_fin_kernel(const float* __restrict__ fgacc, const float* __restrict__ bgacc,
                      const float* __restrict__ denfg, float* __restrict__ fg_pro,
                      float* __restrict__ bg_pro, float* __restrict__ nfg, float* __restrict__ nbg)
{
    __shared__ float sred[16];
    const int b = blockIdx.x, c = threadIdx.x;
    const float d = denfg[b];
    const float fg = fgacc[b * 512 + c] / (d + 5e-4f);
    const float bg = bgacc[b * 512 + c] / ((4096.f - d) + 5e-4f);
    fg_pro[b * 512 + c] = fg; bg_pro[b * 512 + c] = bg;
    float s1 = wsum(fg * fg), s2 = wsum(bg * bg);
    if ((c & 63) == 0) { sred[c >> 6] = s1; sred[8 + (c >> 6)] = s2; }
    __syncthreads();
    if (c == 0) {
        float a = 0.f, bb = 0.f;
        for (int i = 0; i < 8; ++i) { a += sred[i]; bb += sred[8 + i]; }
        nfg[b] = sqrtf(a); nbg[b] = sqrtf(bb);
    }
}

// ---------------- token cosine sims -> softmax pseudo mask ----------------
__global__ __launch_bounds__(256)
void sim_kernel(const u16* __restrict__ k, const float* __restrict__ fg_pro,
                const float* __restrict__ bg_pro, const float* __restrict__ nfg,
                const float* __restrict__ nbg, float* __restrict__ pseudo_fg,
                float* __restrict__ pm)
{
    const int lane = threadIdx.x & 63;
    const int token = blockIdx.x * 4 + (threadIdx.x >> 6);
    const int b = token >> 12, n = token & 4095;
    uint4 u = *(const uint4*)(k + (size_t)token * 512 + lane * 8);
    float kv[8]; unpack8(u, kv);
    const float* fp = fg_pro + b * 512 + lane * 8;
    const float* bp = bg_pro + b * 512 + lane * 8;
    float dfg = 0.f, dbg = 0.f, kk = 0.f;
#pragma unroll
    for (int i = 0; i < 8; ++i) { dfg += kv[i] * fp[i]; dbg += kv[i] * bp[i]; kk += kv[i] * kv[i]; }
    dfg = wsum(dfg); dbg = wsum(dbg); kk = wsum(kk);
    const float nk = fmaxf(sqrtf(kk), 1e-8f);
    const float sfg = 10.f * dfg / (nk * fmaxf(nfg[b], 1e-8f));
    const float sbg = 10.f * dbg / (nk * fmaxf(nbg[b], 1e-8f));
    const float pfg = 1.f / (1.f + expf(sbg - sfg));
    if (lane == 0) {
        pseudo_fg[token] = pfg;
        pm[(size_t)b * 8192 + 4096 + n] = pfg;
        pm[(size_t)b * 8192 + n] = 1.f - pfg;
    }
}

// ---------------- pro1/pro2 mixing ----------------
__global__ __launch_bounds__(512)
void proto2_kernel(const float* __restrict__ q1acc, const float* __restrict__ q2acc,
                   const float* __restrict__ denq1, const float* __restrict__ denq2,
                   const float* __restrict__ fg_pro, const float* __restrict__ nfg,
                   float* __restrict__ pro1, float* __restrict__ pro2)
{
    __shared__ float sred[32];
    __shared__ float s1s, s2s;
    const int b = blockIdx.x, c = threadIdx.x;
    const float q1 = q1acc[b * 512 + c] / (denq1[b] + 5e-4f);
    const float q2 = q2acc[b * 512 + c] / (denq2[b] + 5e-4f);
    const float fg = fg_pro[b * 512 + c];
    float r0 = wsum(q1 * fg), r1 = wsum(q1 * q1), r2 = wsum(q2 * fg), r3 = wsum(q2 * q2);
    const int wv = c >> 6;
    if ((c & 63) == 0) { sred[wv] = r0; sred[8 + wv] = r1; sred[16 + wv] = r2; sred[24 + wv] = r3; }
    __syncthreads();
    if (c == 0) {
        float d1 = 0.f, n1 = 0.f, d2 = 0.f, n2 = 0.f;
        for (int i = 0; i < 8; ++i) { d1 += sred[i]; n1 += sred[8+i]; d2 += sred[16+i]; n2 += sred[24+i]; }
        const float nf = fmaxf(nfg[b], 1e-8f);
        s1s = (d1 / (fmaxf(sqrtf(n1), 1e-8f) * nf) + 1.f) * 0.5f;
        s2s = (d2 / (fmaxf(sqrtf(n2), 1e-8f) * nf) + 1.f) * 0.5f;
    }
    __syncthreads();
    pro1[b * 512 + c] = s1s * fg + (1.f - s1s) * q1;
    pro2[b * 512 + c] = s2s * fg + (1.f - s2s) * q2;
}

// ---------------- scalar fold (fallback path only) ----------------
__global__ __launch_bounds__(256)
void mmcomb2_kernel(const float* __restrict__ Wfx, const float* __restrict__ Wx1,
                    const float* __restrict__ Wx2, u16* __restrict__ Mx,
                    const float* __restrict__ Wfy, const float* __restrict__ Wy1,
                    const float* __restrict__ Wy2, u16* __restrict__ My)
{
    const float* Wf = blockIdx.z ? Wfy : Wfx;
    const float* W1 = blockIdx.z ? Wy1 : Wx1;
    const float* W2 = blockIdx.z ? Wy2 : Wx2;
    u16* Mout = blockIdx.z ? My : Mx;
    const int i = blockIdx.x * 16 + threadIdx.x;
    const int o = blockIdx.y * 16 + threadIdx.y;
    float s = 0.f;
    for (int j = 0; j < 512; ++j) {
        s += Wf[o * 1024 + j]       * W1[j * 1024 + i];
        s += Wf[o * 1024 + 512 + j] * W2[j * 1024 + i];
    }
    Mout[o * 512 + i] = f2bf(s);
}

// ---------------- batched tvec ----------------
__global__ __launch_bounds__(512)
void tvec4_kernel(const float* __restrict__ Wx1, const float* __restrict__ Wx2,
                  const float* __restrict__ Wy1, const float* __restrict__ Wy2,
                  const float* __restrict__ pro1, const float* __restrict__ pro2,
                  float* __restrict__ t1x, float* __restrict__ t2x,
                  float* __restrict__ t1y, float* __restrict__ t2y)
{
    const int z = blockIdx.z;
    const float* W = (z == 0) ? Wx1 : (z == 1) ? Wx2 : (z == 2) ? Wy1 : Wy2;
    const float* p = (z & 1) ? pro2 : pro1;
    float* tout = (z == 0) ? t1x : (z == 1) ? t2x : (z == 2) ? t1y : t2y;
    const int lane = threadIdx.x & 63;
    const int j = blockIdx.x * 8 + (threadIdx.x >> 6);
    const int b = blockIdx.y;
    const float* wr = W + (size_t)j * 1024 + 512 + lane * 8;
    const float* pr = p + b * 512 + lane * 8;
    float4 w0 = *(const float4*)wr, w1 = *(const float4*)(wr + 4);
    float4 p0 = *(const float4*)pr, p1 = *(const float4*)(pr + 4);
    float s = w0.x*p0.x + w0.y*p0.y + w0.z*p0.z + w0.w*p0.w
            + w1.x*p1.x + w1.y*p1.y + w1.z*p1.z + w1.w*p1.w;
    s = wsum(s);
    if (lane == 0) tout[b * 512 + j] = s;
}

// ---------------- batched biascomb ----------------
__global__ __launch_bounds__(512)
void biascomb2_kernel(const float* __restrict__ Wfx, const float* __restrict__ Wfy,
                      const float* __restrict__ t1x, const float* __restrict__ t2x,
                      const float* __restrict__ t1y, const float* __restrict__ t2y,
                      float* __restrict__ bias_x, float* __restrict__ bias_y)
{
    const int z = blockIdx.z;
    const float* Wf = z ? Wfy : Wfx;
    const float* t1 = z ? t1y : t1x;
    const float* t2 = z ? t2y : t2x;
    float* bias = z ? bias_y : bias_x;
    const int lane = threadIdx.x & 63;
    const int o = blockIdx.x * 8 + (threadIdx.x >> 6);
    const int b = blockIdx.y;
    const float* w1 = Wf + (size_t)o * 1024 + lane * 8;
    const float* tp1 = t1 + b * 512 + lane * 8;
    const float* tp2 = t2 + b * 512 + lane * 8;
    float s = 0.f;
#pragma unroll
    for (int h = 0; h < 2; ++h) {
        const float* wv = w1 + h * 512;
        const float* tp = h ? tp2 : tp1;
        float4 a0 = *(const float4*)wv, a1 = *(const float4*)(wv + 4);
        float4 b0 = *(const float4*)tp, b1 = *(const float4*)(tp + 4);
        s += a0.x*b0.x + a0.y*b0.y + a0.z*b0.z + a0.w*b0.w
           + a1.x*b1.x + a1.y*b1.y + a1.z*b1.z + a1.w*b1.w;
    }
    s = wsum(s);
    if (lane == 0) bias[b * 512 + o] = s;
}

extern "C" void kernel_launch(void* const* d_in, const int* in_sizes, int n_in,
                              void* d_out, int out_size, void* d_ws, size_t ws_size,
                              hipStream_t stream)
{
    const float* x   = (const float*)d_in[0];
    const float* y   = (const float*)d_in[1];
    const float* mask= (const float*)d_in[2];
    const float* pp  = (const float*)d_in[3];
    const float* g1  = (const float*)d_in[4];
    const float* be1 = (const float*)d_in[5];
    const float* g2  = (const float*)d_in[6];
    const float* be2 = (const float*)d_in[7];
    const float* Wq  = (const float*)d_in[8];
    const float* Wk  = (const float*)d_in[9];
    const float* Wv  = (const float*)d_in[10];
    const float* Wx1 = (const float*)d_in[11];
    const float* Wx2 = (const float*)d_in[12];
    const float* Wfx = (const float*)d_in[13];
    const float* Wy1 = (const float*)d_in[14];
    const float* Wy2 = (const float*)d_in[15];
    const float* Wfy = (const float*)d_in[16];
    const float* W1x = (const float*)d_in[17];
    const float* b1x = (const float*)d_in[18];
    const float* W2x = (const float*)d_in[19];
    const float* b2x = (const float*)d_in[20];
    const float* W1y = (const float*)d_in[21];
    const float* b1y = (const float*)d_in[22];
    const float* W2y = (const float*)d_in[23];
    const float* b2y = (const float*)d_in[24];

    if (ws_size < 69206016u) return;
    const bool fast = ws_size >= 78643200u;
    const bool huge = ws_size >= 145752064u;

    float* outx = (float*)d_out;
    float* outy = outx + 16777216;
    float* pmf  = outx + 33554432;

    char* wsb = (char*)d_ws;
    float* fsm = (float*)wsb;
    float* fgacc  = fsm;
    float* bgacc  = fsm + 4096;
    float* q1acc  = fsm + 8192;
    float* q2acc  = fsm + 12288;
    float* denq1  = fsm + 16384;
    float* denfg  = fsm + 16392;
    float* denq2  = fsm + 16400;
    float* nfg    = fsm + 16408;
    float* nbg    = fsm + 16416;
    float* fg_pro = fsm + 16424;
    float* bg_pro = fsm + 20520;
    float* pro1   = fsm + 24616;
    float* pro2   = fsm + 28712;
    float* t1x    = fsm + 32808;
    float* t2x    = fsm + 36904;
    float* t1y    = fsm + 41000;
    float* t2y    = fsm + 45096;
    float* bias_x = fsm + 49192;
    float* bias_y = fsm + 53288;
    float* pseudo = fsm + 57384;

    hipMemsetAsync(fsm, 0, 65568, stream);

    if (fast) {
        u16* Mx   = (u16*)(wsb + 0x60000);
        u16* My   = (u16*)(wsb + 0xE0000);
        u16* Wqb  = (u16*)(wsb + 0x160000);
        u16* Wkb  = (u16*)(wsb + 0x1E0000);
        u16* Wvb  = (u16*)(wsb + 0x260000);
        u16* W1xb = (u16*)(wsb + 0x2E0000);
        u16* W2xb = (u16*)(wsb + 0x4E0000);
        u16* W1yb = (u16*)(wsb + 0x6E0000);
        u16* W2yb = (u16*)(wsb + 0x8E0000);
        u16* WS0  = (u16*)(wsb + 0xB00000);
        u16* WS1  = WS0 + 16777216;
        u16* WS2  = WS1 + 16777216;

        u16* OX0 = (u16*)outx;               // raw x bf16
        u16* OX1 = OX0 + 16777216;           // k
        u16* OY  = (u16*)outy;               // raw y bf16, then hidden-x

        // transient M-fold buffers in WS0 (dead before LN1 writes WS0)
        u16* Wfxb = WS0;                     // 512x1024 bf16
        u16* Wfyb = WS0 + 524288;
        u16* Wtx  = WS0 + 1048576;           // 512x1024 bf16 (transposed [i][j])
        u16* Wty  = WS0 + 1572864;

        cvt3_kernel<<<dim3(128, 3), 256, 0, stream>>>(Wq, Wk, Wv, Wqb, Wkb, Wvb, 32768);
        cvt4_kernel<<<dim3(512, 4), 256, 0, stream>>>(W1x, W2x, W1y, W2y, W1xb, W2xb, W1yb, W2yb, 131072);
        cvt2_kernel<<<dim3(256, 2), 256, 0, stream>>>(Wfx, Wfy, Wfxb, Wfyb, 65536);
        wtrans_kernel<<<dim3(16, 16, 4), dim3(32, 8), 0, stream>>>(Wx1, Wx2, Wy1, Wy2, Wtx, Wty);
        // M = Wf @ [W1;W2] via MFMA: A=Wfb[o][j], B=Wt[i][j], K=1024
        gemm2z_kernel<0, true><<<dim3(4, 4, 2), 256, 0, stream>>>(
            Wfxb, Wtx, Mx, nullptr, nullptr,
            Wfyb, Wty, My, nullptr, nullptr, 512, 1024);

        // LN1 batched (disjoint buffers): x -> WS0 (+raw OX0), y -> WS1 (+raw OY)
        ln2_kernel<false, true><<<dim3(8192, 2), 256, 0, stream>>>(x, WS0, OX0, y, WS1, OY, g1, be1);

        dim3 gq(256, 2);
        gemm3_red_kernel<0><<<gq, 512, 0, stream>>>(WS1, Wqb, 512, mask, nullptr, fgacc, bgacc);
        rowsum2_kernel<<<dim3(8, 2), 256, 0, stream>>>(mask, denfg, pp, denq2);
        proto_fin_kernel<<<8, 512, 0, stream>>>(fgacc, bgacc, denfg, fg_pro, bg_pro, nfg, nbg);

        gemm3_kernel<0, true><<<gq, 512, 0, stream>>>(WS0, Wkb, OX1, 512, 512, nullptr, nullptr, nullptr);
        sim_kernel<<<8192, 256, 0, stream>>>(OX1, fg_pro, bg_pro, nfg, nbg, pseudo, pmf);
        rowsum_kernel<<<8, 256, 0, stream>>>(pseudo, denq1);

        gemm3_red_kernel<1><<<gq, 512, 0, stream>>>(WS0, Wvb, 512, pseudo, pp, q1acc, q2acc);
        proto2_kernel<<<8, 512, 0, stream>>>(q1acc, q2acc, denq1, denq2, fg_pro, nfg, pro1, pro2);

        tvec4_kernel<<<dim3(64, 8, 4), 512, 0, stream>>>(Wx1, Wx2, Wy1, Wy2, pro1, pro2, t1x, t2x, t1y, t2y);
        biascomb2_kernel<<<dim3(64, 8, 2), 512, 0, stream>>>(Wfx, Wfy, t1x, t2x, t1y, t2y, bias_x, bias_y);

        // merges + LN2 sequential (ly lives in WS0, outside d_out)
        gemm3_kernel<1, true><<<gq, 512, 0, stream>>>(OX0, Mx, WS0, 512, 512, bias_x, nullptr, x);  // xm -> WS0
        ln_kernel<true, false><<<8192, 256, 0, stream>>>(WS0, WS1, g2, be2, nullptr);               // lx -> WS1
        gemm3_kernel<1, true><<<gq, 512, 0, stream>>>(OY, My, WS0, 512, 512, bias_y, nullptr, y);   // ym -> WS0
        ln_kernel<true, false><<<8192, 256, 0, stream>>>(WS0, WS0, g2, be2, nullptr);               // ly in-place

        // x-MLP: 2 chunks of 16384 rows, hidden in OY (raw y dead)
        for (int ch = 0; ch < 2; ++ch) {
            const size_t ro = (size_t)ch * 16384 * 512;
            gemm3_kernel<2, true><<<dim3(128, 8), 512, 0, stream>>>(WS1 + ro, W1xb, OY, 2048, 512, nullptr, b1x, nullptr);
            gemm2_kernel<3, false><<<dim3(128, 4), 256, 0, stream>>>(OY, W2xb, outx + ro, 512, 2048, nullptr, b2x, x + ro);
        }

        if (huge) {
            for (int ch = 0; ch < 2; ++ch) {
                const size_t ro = (size_t)ch * 16384 * 512;
                gemm3_kernel<2, true><<<dim3(128, 8), 512, 0, stream>>>(WS0 + ro, W1yb, WS2, 2048, 512, nullptr, b1y, nullptr);
                gemm2_kernel<3, false><<<dim3(128, 4), 256, 0, stream>>>(WS2, W2yb, outy + ro, 512, 2048, nullptr, b2y, y + ro);
            }
        } else {
            for (int ch = 0; ch < 4; ++ch) {
                const size_t ro = (size_t)ch * 8192 * 512;
                gemm3_kernel<2, true><<<dim3(64, 8), 512, 0, stream>>>(WS0 + ro, W1yb, WS1, 2048, 512, nullptr, b1y, nullptr);
                gemm2_kernel<3, false><<<dim3(64, 4), 256, 0, stream>>>(WS1, W2yb, outy + ro, 512, 2048, nullptr, b2y, y + ro);
            }
        }
    } else {
        // ---- fallback: round-4 path ----
        u16* Mx  = (u16*)(wsb + 360608);
        u16* My  = (u16*)(wsb + 884896);
        u16* WS0 = (u16*)(wsb + 2097152);
        u16* WS1 = (u16*)(wsb + 35651584);

        ln_kernel<false, false><<<8192, 256, 0, stream>>>(x, WS0, g1, be1, nullptr);
        ln_kernel<false, false><<<8192, 256, 0, stream>>>(y, WS1, g1, be1, nullptr);

        dim3 g512(256, 4);
        gemm_red_kernel<0><<<g512, 256, 0, stream>>>(WS1, Wq, 512, mask, nullptr, fgacc, bgacc);
        rowsum_kernel<<<8, 256, 0, stream>>>(mask, denfg);
        rowsum_kernel<<<8, 256, 0, stream>>>(pp, denq2);
        proto_fin_kernel<<<8, 512, 0, stream>>>(fgacc, bgacc, denfg, fg_pro, bg_pro, nfg, nbg);

        gemm_kernel<0, true, false, true><<<g512, 256, 0, stream>>>(WS0, Wk, WS1, 512, 512, nullptr, nullptr, nullptr);
        sim_kernel<<<8192, 256, 0, stream>>>(WS1, fg_pro, bg_pro, nfg, nbg, pseudo, pmf);
        rowsum_kernel<<<8, 256, 0, stream>>>(pseudo, denq1);

        gemm_red_kernel<1><<<g512, 256, 0, stream>>>(WS0, Wv, 512, pseudo, pp, q1acc, q2acc);
        proto2_kernel<<<8, 512, 0, stream>>>(q1acc, q2acc, denq1, denq2, fg_pro, nfg, pro1, pro2);

        mmcomb2_kernel<<<dim3(32, 32, 2), dim3(16, 16), 0, stream>>>(Wfx, Wx1, Wx2, Mx, Wfy, Wy1, Wy2, My);
        tvec4_kernel<<<dim3(64, 8, 4), 512, 0, stream>>>(Wx1, Wx2, Wy1, Wy2, pro1, pro2, t1x, t2x, t1y, t2y);
        biascomb2_kernel<<<dim3(64, 8, 2), 512, 0, stream>>>(Wfx, Wfy, t1x, t2x, t1y, t2y, bias_x, bias_y);

        gemm_kernel<1, false, true, true><<<g512, 256, 0, stream>>>(x, Mx, WS0, 512, 512, bias_x, nullptr, x);
        ln_kernel<true, false><<<8192, 256, 0, stream>>>(WS0, WS1, g2, be2, nullptr);
        for (int ch = 0; ch < 4; ++ch) {
            const size_t ro = (size_t)ch * 8192 * 512;
            gemm_kernel<2, true, false, true><<<dim3(64, 16), 256, 0, stream>>>(WS1 + ro, W1x, WS0, 2048, 512, nullptr, b1x, nullptr);
            gemm_kernel<3, true, false, false><<<dim3(64, 4), 256, 0, stream>>>(WS0, W2x, outx + ro, 512, 2048, nullptr, b2x, x + ro);
        }
        gemm_kernel<1, false, true, true><<<g512, 256, 0, stream>>>(y, My, WS0, 512, 512, bias_y, nullptr, y);
        ln_kernel<true, false><<<8192, 256, 0, stream>>>(WS0, WS1, g2, be2, nullptr);
        for (int ch = 0; ch < 4; ++ch) {
            const size_t ro = (size_t)ch * 8192 * 512;
            gemm_kernel<2, true, false, true><<<dim3(64, 16), 256, 0, stream>>>(WS1 + ro, W1y, WS0, 2048, 512, nullptr, b1y, nullptr);
            gemm_kernel<3, true, false, false><<<dim3(64, 4), 256, 0, stream>>>(WS0, W2y, outy + ro, 512, 2048, nullptr, b2y, y + ro);
        }
    }
    (void)in_sizes; (void)n_in; (void)out_size;
}

// Round 19
// 772.462 us; speedup vs baseline: 1.1758x; 1.0026x over previous
//
#include <hip/hip_runtime.h>
#include <stdint.h>

typedef unsigned short u16;
typedef unsigned int   u32;

typedef __attribute__((ext_vector_type(8))) __bf16 bf16x8;
typedef __attribute__((ext_vector_type(4))) float  f32x4;

#define GLD_LDS(g, l) __builtin_amdgcn_global_load_lds( \
    (__attribute__((address_space(1))) void*)(g),        \
    (__attribute__((address_space(3))) void*)(l), 16, 0, 0)

__device__ __forceinline__ float bf2f(u16 h) {
    union { u32 u; float f; } c; c.u = ((u32)h) << 16; return c.f;
}
__device__ __forceinline__ u16 f2bf(float f) {
    union { float f; u32 u; } c; c.f = f;
    return (u16)((c.u + 0x7FFFu + ((c.u >> 16) & 1u)) >> 16);
}
__device__ __forceinline__ u32 pack2(float a, float b) {
    return (u32)f2bf(a) | ((u32)f2bf(b) << 16);
}
__device__ __forceinline__ uint4 pack8(float4 a, float4 b) {
    return make_uint4(pack2(a.x, a.y), pack2(a.z, a.w), pack2(b.x, b.y), pack2(b.z, b.w));
}
__device__ __forceinline__ void unpack8(uint4 u, float v[8]) {
    v[0] = bf2f((u16)(u.x & 0xffff)); v[1] = bf2f((u16)(u.x >> 16));
    v[2] = bf2f((u16)(u.y & 0xffff)); v[3] = bf2f((u16)(u.y >> 16));
    v[4] = bf2f((u16)(u.z & 0xffff)); v[5] = bf2f((u16)(u.z >> 16));
    v[6] = bf2f((u16)(u.w & 0xffff)); v[7] = bf2f((u16)(u.w >> 16));
}
__device__ __forceinline__ float wsum(float v) {
#pragma unroll
    for (int o = 32; o > 0; o >>= 1) v += __shfl_xor(v, o, 64);
    return v;
}
// fast tanh-form GELU
__device__ __forceinline__ float fast_gelu(float x) {
    const float u = x * (1.f + 0.044715f * x * x);
    return x / (1.f + __expf(-1.5957691216f * u));
}

// ---------------- f32 -> bf16 convert, batched over z ----------------
__global__ __launch_bounds__(256)
void cvt4_kernel(const float* __restrict__ a, const float* __restrict__ b,
                 const float* __restrict__ c, const float* __restrict__ d,
                 u16* __restrict__ oa, u16* __restrict__ ob,
                 u16* __restrict__ oc, u16* __restrict__ od, int n8)
{
    const int i = blockIdx.x * 256 + threadIdx.x;
    if (i >= n8) return;
    const int z = blockIdx.y;
    const float* in = (z == 0) ? a : (z == 1) ? b : (z == 2) ? c : d;
    u16* out = (z == 0) ? oa : (z == 1) ? ob : (z == 2) ? oc : od;
    const float* p = in + (size_t)i * 8;
    float4 u = *(const float4*)p, v = *(const float4*)(p + 4);
    *(uint4*)(out + (size_t)i * 8) = pack8(u, v);
}
__global__ __launch_bounds__(256)
void cvt3_kernel(const float* __restrict__ a, const float* __restrict__ b,
                 const float* __restrict__ c,
                 u16* __restrict__ oa, u16* __restrict__ ob, u16* __restrict__ oc, int n8)
{
    const int i = blockIdx.x * 256 + threadIdx.x;
    if (i >= n8) return;
    const int z = blockIdx.y;
    const float* in = (z == 0) ? a : (z == 1) ? b : c;
    u16* out = (z == 0) ? oa : (z == 1) ? ob : oc;
    const float* p = in + (size_t)i * 8;
    float4 u = *(const float4*)p, v = *(const float4*)(p + 4);
    *(uint4*)(out + (size_t)i * 8) = pack8(u, v);
}
__global__ __launch_bounds__(256)
void cvt2_kernel(const float* __restrict__ a, const float* __restrict__ b,
                 u16* __restrict__ oa, u16* __restrict__ ob, int n8)
{
    const int i = blockIdx.x * 256 + threadIdx.x;
    if (i >= n8) return;
    const float* in = blockIdx.y ? b : a;
    u16* out = blockIdx.y ? ob : oa;
    const float* p = in + (size_t)i * 8;
    float4 u = *(const float4*)p, v = *(const float4*)(p + 4);
    *(uint4*)(out + (size_t)i * 8) = pack8(u, v);
}

// ---------------- transpose first-half columns of W (512x1024 f32) -> bf16 Wt[i][j] ----------------
__global__ __launch_bounds__(256)
void wtrans_kernel(const float* __restrict__ W1x, const float* __restrict__ W2x,
                   const float* __restrict__ W1y, const float* __restrict__ W2y,
                   u16* __restrict__ Wtx, u16* __restrict__ Wty)
{
    __shared__ float tile[32][33];
    const int z = blockIdx.z;
    const float* src = (z == 0) ? W1x : (z == 1) ? W2x : (z == 2) ? W1y : W2y;
    u16* dst = (z < 2) ? Wtx : Wty;
    const int joff = (z & 1) * 512;
    const int j0 = blockIdx.y * 32;
    const int i0 = blockIdx.x * 32;
    for (int r = threadIdx.y; r < 32; r += 8)
        tile[r][threadIdx.x] = src[(size_t)(j0 + r) * 1024 + i0 + threadIdx.x];
    __syncthreads();
    for (int r = threadIdx.y; r < 32; r += 8)
        dst[(size_t)(i0 + r) * 1024 + joff + j0 + threadIdx.x] = f2bf(tile[threadIdx.x][r]);
}

// ---------------- LayerNorm core ----------------
template<bool IN16, bool RAW>
__device__ __forceinline__ void ln_body(const void* in, u16* out,
                                        const float* g, const float* be, u16* raw_out)
{
    const int lane = threadIdx.x & 63;
    const size_t row = (size_t)blockIdx.x * 4 + (threadIdx.x >> 6);
    const size_t base = row * 512 + lane * 8;
    float v[8];
    if constexpr (IN16) {
        unpack8(*(const uint4*)((const u16*)in + base), v);
    } else {
        const float* p = (const float*)in + base;
        float4 a = *(const float4*)p, b = *(const float4*)(p + 4);
        v[0]=a.x; v[1]=a.y; v[2]=a.z; v[3]=a.w; v[4]=b.x; v[5]=b.y; v[6]=b.z; v[7]=b.w;
    }
    if constexpr (RAW) {
        u32 ro[4];
#pragma unroll
        for (int i = 0; i < 4; ++i) ro[i] = pack2(v[2*i], v[2*i+1]);
        *(uint4*)(raw_out + base) = make_uint4(ro[0], ro[1], ro[2], ro[3]);
    }
    float s = 0.f, ss = 0.f;
#pragma unroll
    for (int i = 0; i < 8; ++i) { s += v[i]; ss += v[i] * v[i]; }
    s = wsum(s); ss = wsum(ss);
    const float mean = s * (1.f / 512.f);
    const float rstd = rsqrtf(ss * (1.f / 512.f) - mean * mean + 1e-5f);
    const float* gp = g + lane * 8;
    const float* bp = be + lane * 8;
    u32 o[4];
#pragma unroll
    for (int i = 0; i < 4; ++i) {
        u16 lo = f2bf((v[2*i]   - mean) * rstd * gp[2*i]   + bp[2*i]);
        u16 hi = f2bf((v[2*i+1] - mean) * rstd * gp[2*i+1] + bp[2*i+1]);
        o[i] = (u32)lo | ((u32)hi << 16);
    }
    *(uint4*)(out + base) = make_uint4(o[0], o[1], o[2], o[3]);
}

template<bool IN16, bool RAW>
__global__ __launch_bounds__(256)
void ln_kernel(const void* __restrict__ in, u16* __restrict__ out,
               const float* __restrict__ g, const float* __restrict__ be,
               u16* __restrict__ raw_out)
{
    ln_body<IN16, RAW>(in, out, g, be, raw_out);
}

template<bool IN16, bool RAW>
__global__ __launch_bounds__(256)
void ln2_kernel(const void* __restrict__ in0, u16* __restrict__ out0, u16* __restrict__ raw0,
                const void* __restrict__ in1, u16* __restrict__ out1, u16* __restrict__ raw1,
                const float* __restrict__ g, const float* __restrict__ be)
{
    if (blockIdx.y == 0) ln_body<IN16, RAW>(in0, out0, g, be, raw0);
    else                 ln_body<IN16, RAW>(in1, out1, g, be, raw1);
}

// ---- reg-staging helper (fallback path) ----
template<bool IS16>
__device__ __forceinline__ void load_pair(const void* P, size_t off, size_t rstep,
                                          uint4& r0, uint4& r1)
{
    if constexpr (IS16) {
        const u16* p = (const u16*)P + off;
        r0 = *(const uint4*)p;
        r1 = *(const uint4*)(p + rstep);
    } else {
        const float* p = (const float*)P + off;
        float4 a0 = *(const float4*)p,           a1 = *(const float4*)(p + 4);
        float4 b0 = *(const float4*)(p + rstep), b1 = *(const float4*)(p + rstep + 4);
        r0 = pack8(a0, a1);
        r1 = pack8(b0, b1);
    }
}

// ===== FAST GEMM v3 body: 128x256 tile, 8 waves, gld_lds + XOR swizzle, 2-stage dbuf =====
template<int EPI, bool OUT16>
__device__ __forceinline__ void gemm3_body(const u16* A, const u16* B, void* Cp, int N, int K,
                                           const float* bias_b, const float* bias_v, const float* skip,
                                           u16 sA[2][128 * 32], u16 sB[2][256 * 32])
{
    const int t = threadIdx.x;
    const int w = t >> 6;
    const int lane = t & 63;
    const int lr = lane & 15;
    const int lk = lane >> 4;
    const int bm0 = blockIdx.x * 128;
    const int bn0 = blockIdx.y * 256;
    const int wrow = (w >> 2) * 64;
    const int wcol = (w & 3) * 64;

    f32x4 acc[4][4];
#pragma unroll
    for (int m = 0; m < 4; ++m)
#pragma unroll
        for (int n = 0; n < 4; ++n) acc[m][n] = (f32x4){0.f, 0.f, 0.f, 0.f};

    const int scol = ((t & 3) ^ ((t >> 3) & 3)) * 8;
    const u16* gA = A + (size_t)(bm0 + (t >> 2)) * K + scol;
    const u16* gB = B + (size_t)(bn0 + (t >> 2)) * K + scol;
    const size_t rstep = (size_t)128 * K;
    const int wo = w << 9;
    const int sa = (lk ^ ((lr >> 1) & 3)) * 8;

    GLD_LDS(gA, sA[0] + wo);
    GLD_LDS(gB, sB[0] + wo);
    GLD_LDS(gB + rstep, sB[0] + 4096 + wo);
    __syncthreads();

    int cur = 0;
    for (int kt = 32; kt <= K; kt += 32) {
        if (kt < K) {
            const int nxt = cur ^ 1;
            GLD_LDS(gA + kt, sA[nxt] + wo);
            GLD_LDS(gB + kt, sB[nxt] + wo);
            GLD_LDS(gB + kt + rstep, sB[nxt] + 4096 + wo);
        }
        bf16x8 af[4], bfr[4];
#pragma unroll
        for (int m = 0; m < 4; ++m)
            af[m] = *(const bf16x8*)&sA[cur][(wrow + m * 16 + lr) * 32 + sa];
#pragma unroll
        for (int n = 0; n < 4; ++n)
            bfr[n] = *(const bf16x8*)&sB[cur][(wcol + n * 16 + lr) * 32 + sa];
#pragma unroll
        for (int m = 0; m < 4; ++m)
#pragma unroll
            for (int n = 0; n < 4; ++n)
                acc[m][n] = __builtin_amdgcn_mfma_f32_16x16x32_bf16(af[m], bfr[n], acc[m][n], 0, 0, 0);
        if (kt < K) { __syncthreads(); cur ^= 1; }
    }

#pragma unroll
    for (int m = 0; m < 4; ++m) {
#pragma unroll
        for (int n = 0; n < 4; ++n) {
            const int col = bn0 + wcol + n * 16 + lr;
#pragma unroll
            for (int r = 0; r < 4; ++r) {
                const int row = bm0 + wrow + m * 16 + lk * 4 + r;
                const size_t idx = (size_t)row * N + col;
                float vv = acc[m][n][r];
                if (EPI == 1) vv += bias_b[(size_t)(row >> 12) * N + col] + skip[idx];
                if (EPI == 2) { vv += bias_v[col]; vv = fast_gelu(vv); }
                if (EPI == 3) vv += bias_v[col] + skip[idx];
                if (OUT16) ((u16*)Cp)[idx] = f2bf(vv);
                else       ((float*)Cp)[idx] = vv;
            }
        }
    }
}

// ===== gemm3_red body =====
template<int WM>
__device__ __forceinline__ void gemm3red_body(const u16* A, const u16* B, int K,
                                              const float* wa, const float* wb,
                                              float* acc1, float* acc2,
                                              u16 sA[2][128 * 32], u16 sB[2][256 * 32],
                                              float sred[8][2][64])
{
    const int t = threadIdx.x;
    const int w = t >> 6;
    const int lane = t & 63;
    const int lr = lane & 15;
    const int lk = lane >> 4;
    const int bm0 = blockIdx.x * 128;
    const int bn0 = blockIdx.y * 256;
    const int wrow = (w >> 2) * 64;
    const int wcol = (w & 3) * 64;

    f32x4 acc[4][4];
#pragma unroll
    for (int m = 0; m < 4; ++m)
#pragma unroll
        for (int n = 0; n < 4; ++n) acc[m][n] = (f32x4){0.f, 0.f, 0.f, 0.f};

    const int scol = ((t & 3) ^ ((t >> 3) & 3)) * 8;
    const u16* gA = A + (size_t)(bm0 + (t >> 2)) * K + scol;
    const u16* gB = B + (size_t)(bn0 + (t >> 2)) * K + scol;
    const size_t rstep = (size_t)128 * K;
    const int wo = w << 9;
    const int sa = (lk ^ ((lr >> 1) & 3)) * 8;

    GLD_LDS(gA, sA[0] + wo);
    GLD_LDS(gB, sB[0] + wo);
    GLD_LDS(gB + rstep, sB[0] + 4096 + wo);
    __syncthreads();

    int cur = 0;
    for (int kt = 32; kt <= K; kt += 32) {
        if (kt < K) {
            const int nxt = cur ^ 1;
            GLD_LDS(gA + kt, sA[nxt] + wo);
            GLD_LDS(gB + kt, sB[nxt] + wo);
            GLD_LDS(gB + kt + rstep, sB[nxt] + 4096 + wo);
        }
        bf16x8 af[4], bfr[4];
#pragma unroll
        for (int m = 0; m < 4; ++m)
            af[m] = *(const bf16x8*)&sA[cur][(wrow + m * 16 + lr) * 32 + sa];
#pragma unroll
        for (int n = 0; n < 4; ++n)
            bfr[n] = *(const bf16x8*)&sB[cur][(wcol + n * 16 + lr) * 32 + sa];
#pragma unroll
        for (int m = 0; m < 4; ++m)
#pragma unroll
            for (int n = 0; n < 4; ++n)
                acc[m][n] = __builtin_amdgcn_mfma_f32_16x16x32_bf16(af[m], bfr[n], acc[m][n], 0, 0, 0);
        if (kt < K) { __syncthreads(); cur ^= 1; }
    }

    float w1v[16], w2v[16];
#pragma unroll
    for (int m = 0; m < 4; ++m)
#pragma unroll
        for (int r = 0; r < 4; ++r) {
            const int row = bm0 + wrow + m * 16 + lk * 4 + r;
            if (WM == 0) { float mm = wa[row]; w1v[m*4+r] = mm; w2v[m*4+r] = 1.f - mm; }
            else         { w1v[m*4+r] = wa[row]; w2v[m*4+r] = wb[row]; }
        }
    __syncthreads();
#pragma unroll
    for (int n = 0; n < 4; ++n) {
        float s1 = 0.f, s2 = 0.f;
#pragma unroll
        for (int m = 0; m < 4; ++m)
#pragma unroll
            for (int r = 0; r < 4; ++r) {
                s1 += acc[m][n][r] * w1v[m*4+r];
                s2 += acc[m][n][r] * w2v[m*4+r];
            }
        s1 += __shfl_xor(s1, 16, 64); s1 += __shfl_xor(s1, 32, 64);
        s2 += __shfl_xor(s2, 16, 64); s2 += __shfl_xor(s2, 32, 64);
        if (lk == 0) { sred[w][0][n*16+lr] = s1; sred[w][1][n*16+lr] = s2; }
    }
    __syncthreads();
    if (t < 256) {
        const int strip = t >> 6, c = t & 63;
        const float v1 = sred[strip][0][c] + sred[strip + 4][0][c];
        const float v2 = sred[strip][1][c] + sred[strip + 4][1][c];
        const int col = bn0 + strip * 64 + c;
        const int b = bm0 >> 12;
        atomicAdd(&acc1[b * 512 + col], v1);
        atomicAdd(&acc2[b * 512 + col], v2);
    }
}

template<int EPI, bool OUT16>
__global__ __launch_bounds__(512)
void gemm3_kernel(const u16* __restrict__ A, const u16* __restrict__ B,
                  void* __restrict__ Cp, int N, int K,
                  const float* __restrict__ bias_b,
                  const float* __restrict__ bias_v,
                  const float* __restrict__ skip)
{
    __shared__ u16 sA[2][128 * 32];
    __shared__ u16 sB[2][256 * 32];
    gemm3_body<EPI, OUT16>(A, B, Cp, N, K, bias_b, bias_v, skip, sA, sB);
}

template<int WM>
__global__ __launch_bounds__(512)
void gemm3_red_kernel(const u16* __restrict__ A, const u16* __restrict__ B, int K,
                      const float* __restrict__ wa, const float* __restrict__ wb,
                      float* __restrict__ acc1, float* __restrict__ acc2)
{
    __shared__ u16 sA[2][128 * 32];
    __shared__ u16 sB[2][256 * 32];
    __shared__ float sred[8][2][64];
    gemm3red_body<WM>(A, B, K, wa, wb, acc1, acc2, sA, sB, sred);
}

// mixed launch: z=0 q-reduction GEMM, z=1 plain k GEMM (independent inputs/outputs)
__global__ __launch_bounds__(512)
void qk_mix_kernel(const u16* __restrict__ Ayn, const u16* __restrict__ Wqb,
                   const float* __restrict__ mask, float* __restrict__ fgacc, float* __restrict__ bgacc,
                   const u16* __restrict__ Axn, const u16* __restrict__ Wkb, u16* __restrict__ Ck,
                   int N, int K)
{
    __shared__ u16 sA[2][128 * 32];
    __shared__ u16 sB[2][256 * 32];
    __shared__ float sred[8][2][64];
    if (blockIdx.z == 0)
        gemm3red_body<0>(Ayn, Wqb, K, mask, nullptr, fgacc, bgacc, sA, sB, sred);
    else
        gemm3_body<0, true>(Axn, Wkb, Ck, N, K, nullptr, nullptr, nullptr, sA, sB);
}

// z-batched pair of gemm3 (disjoint buffers only)
template<int EPI, bool OUT16>
__global__ __launch_bounds__(512)
void gemm3z_kernel(const u16* __restrict__ A0, const u16* __restrict__ B0, void* __restrict__ C0,
                   const float* __restrict__ bb0, const float* __restrict__ bv0, const float* __restrict__ sk0,
                   const u16* __restrict__ A1, const u16* __restrict__ B1, void* __restrict__ C1,
                   const float* __restrict__ bb1, const float* __restrict__ bv1, const float* __restrict__ sk1,
                   int N, int K)
{
    __shared__ u16 sA[2][128 * 32];
    __shared__ u16 sB[2][256 * 32];
    if (blockIdx.z == 0) gemm3_body<EPI, OUT16>(A0, B0, C0, N, K, bb0, bv0, sk0, sA, sB);
    else                 gemm3_body<EPI, OUT16>(A1, B1, C1, N, K, bb1, bv1, sk1, sA, sB);
}

// ===== FAST GEMM v2: 128x128 tile, 4 waves, 2-stage dbuf (W2, M-fold) =====
template<int EPI, bool OUT16>
__device__ __forceinline__ void gemm2_body(const u16* A, const u16* B, void* Cp, int N, int K,
                                           const float* bias_v, const float* skip,
                                           u16 sA[2][128 * 32], u16 sB[2][128 * 32])
{
    const int t = threadIdx.x;
    const int w = t >> 6;
    const int lane = t & 63;
    const int lr = lane & 15;
    const int lk = lane >> 4;
    const int bm0 = blockIdx.x * 128;
    const int bn0 = blockIdx.y * 128;
    const int wrow = (w >> 1) * 64;
    const int wcol = (w & 1) * 64;

    f32x4 acc[4][4];
#pragma unroll
    for (int m = 0; m < 4; ++m)
#pragma unroll
        for (int n = 0; n < 4; ++n) acc[m][n] = (f32x4){0.f, 0.f, 0.f, 0.f};

    const int scol = ((t & 3) ^ ((t >> 3) & 3)) * 8;
    const u16* gA = A + (size_t)(bm0 + (t >> 2)) * K + scol;
    const u16* gB = B + (size_t)(bn0 + (t >> 2)) * K + scol;
    const size_t rstep = (size_t)64 * K;
    const int wo = w << 9;
    const int sa = (lk ^ ((lr >> 1) & 3)) * 8;

    GLD_LDS(gA, sA[0] + wo); GLD_LDS(gA + rstep, sA[0] + wo + 2048);
    GLD_LDS(gB, sB[0] + wo); GLD_LDS(gB + rstep, sB[0] + wo + 2048);
    __syncthreads();

    int cur = 0;
    for (int kt = 32; kt <= K; kt += 32) {
        if (kt < K) {
            const int nxt = cur ^ 1;
            GLD_LDS(gA + kt, sA[nxt] + wo); GLD_LDS(gA + kt + rstep, sA[nxt] + wo + 2048);
            GLD_LDS(gB + kt, sB[nxt] + wo); GLD_LDS(gB + kt + rstep, sB[nxt] + wo + 2048);
        }
        bf16x8 af[4], bfr[4];
#pragma unroll
        for (int m = 0; m < 4; ++m)
            af[m] = *(const bf16x8*)&sA[cur][(wrow + m * 16 + lr) * 32 + sa];
#pragma unroll
        for (int n = 0; n < 4; ++n)
            bfr[n] = *(const bf16x8*)&sB[cur][(wcol + n * 16 + lr) * 32 + sa];
#pragma unroll
        for (int m = 0; m < 4; ++m)
#pragma unroll
            for (int n = 0; n < 4; ++n)
                acc[m][n] = __builtin_amdgcn_mfma_f32_16x16x32_bf16(af[m], bfr[n], acc[m][n], 0, 0, 0);
        if (kt < K) { __syncthreads(); cur ^= 1; }
    }

#pragma unroll
    for (int m = 0; m < 4; ++m) {
#pragma unroll
        for (int n = 0; n < 4; ++n) {
            const int col = bn0 + wcol + n * 16 + lr;
#pragma unroll
            for (int r = 0; r < 4; ++r) {
                const int row = bm0 + wrow + m * 16 + lk * 4 + r;
                const size_t idx = (size_t)row * N + col;
                float vv = acc[m][n][r];
                if (EPI == 2) { vv += bias_v[col]; vv = fast_gelu(vv); }
                if (EPI == 3) vv += bias_v[col] + skip[idx];
                if (OUT16) ((u16*)Cp)[idx] = f2bf(vv);
                else       ((float*)Cp)[idx] = vv;
            }
        }
    }
}

template<int EPI, bool OUT16>
__global__ __launch_bounds__(256)
void gemm2_kernel(const u16* __restrict__ A, const u16* __restrict__ B,
                  void* __restrict__ Cp, int N, int K,
                  const float* __restrict__ bias_b,
                  const float* __restrict__ bias_v,
                  const float* __restrict__ skip)
{
    __shared__ u16 sA[2][128 * 32];
    __shared__ u16 sB[2][128 * 32];
    gemm2_body<EPI, OUT16>(A, B, Cp, N, K, bias_v, skip, sA, sB);
    (void)bias_b;
}

template<int EPI, bool OUT16>
__global__ __launch_bounds__(256)
void gemm2z_kernel(const u16* __restrict__ A0, const u16* __restrict__ B0, void* __restrict__ C0,
                   const float* __restrict__ bv0, const float* __restrict__ sk0,
                   const u16* __restrict__ A1, const u16* __restrict__ B1, void* __restrict__ C1,
                   const float* __restrict__ bv1, const float* __restrict__ sk1,
                   int N, int K)
{
    __shared__ u16 sA[2][128 * 32];
    __shared__ u16 sB[2][128 * 32];
    if (blockIdx.z == 0) gemm2_body<EPI, OUT16>(A0, B0, C0, N, K, bv0, sk0, sA, sB);
    else                 gemm2_body<EPI, OUT16>(A1, B1, C1, N, K, bv1, sk1, sA, sB);
}

// ================= OLD reg-staged GEMM (fallback path only) =================
template<int EPI, bool A16, bool B16, bool OUT16>
__global__ __launch_bounds__(256)
void gemm_kernel(const void* __restrict__ Ap, const void* __restrict__ Wp,
                 void* __restrict__ Cp, int N, int K,
                 const float* __restrict__ bias_b,
                 const float* __restrict__ bias_v,
                 const float* __restrict__ skip)
{
    __shared__ u16 sA[128 * 32];
    __shared__ u16 sB[128 * 32];
    const int t = threadIdx.x;
    const int w = t >> 6;
    const int lane = t & 63;
    const int lr = lane & 15;
    const int lk = lane >> 4;
    const int bm0 = blockIdx.x * 128;
    const int bn0 = blockIdx.y * 128;
    const int wrow = (w >> 1) * 64;
    const int wcol = (w & 1) * 64;

    f32x4 acc[4][4];
#pragma unroll
    for (int m = 0; m < 4; ++m)
#pragma unroll
        for (int n = 0; n < 4; ++n) acc[m][n] = (f32x4){0.f, 0.f, 0.f, 0.f};

    const size_t aoff = (size_t)(bm0 + (t >> 2)) * K + (t & 3) * 8;
    const size_t boff = (size_t)(bn0 + (t >> 2)) * K + (t & 3) * 8;
    const size_t rstep = (size_t)64 * K;
    u16* dA = sA + 8 * t;
    u16* dB = sB + 8 * t;

    for (int kt = 0; kt < K; kt += 32) {
        uint4 ra0, ra1, rb0, rb1;
        load_pair<A16>(Ap, aoff + kt, rstep, ra0, ra1);
        load_pair<B16>(Wp, boff + kt, rstep, rb0, rb1);
        __syncthreads();
        *(uint4*)dA = ra0; *(uint4*)(dA + 2048) = ra1;
        *(uint4*)dB = rb0; *(uint4*)(dB + 2048) = rb1;
        __syncthreads();
        bf16x8 af[4], bfr[4];
#pragma unroll
        for (int m = 0; m < 4; ++m)
            af[m] = *(const bf16x8*)&sA[(wrow + m * 16 + lr) * 32 + lk * 8];
#pragma unroll
        for (int n = 0; n < 4; ++n)
            bfr[n] = *(const bf16x8*)&sB[(wcol + n * 16 + lr) * 32 + lk * 8];
#pragma unroll
        for (int m = 0; m < 4; ++m)
#pragma unroll
            for (int n = 0; n < 4; ++n)
                acc[m][n] = __builtin_amdgcn_mfma_f32_16x16x32_bf16(af[m], bfr[n], acc[m][n], 0, 0, 0);
    }

#pragma unroll
    for (int m = 0; m < 4; ++m) {
#pragma unroll
        for (int n = 0; n < 4; ++n) {
            const int col = bn0 + wcol + n * 16 + lr;
#pragma unroll
            for (int r = 0; r < 4; ++r) {
                const int row = bm0 + wrow + m * 16 + lk * 4 + r;
                const size_t idx = (size_t)row * N + col;
                float vv = acc[m][n][r];
                if (EPI == 1) vv += bias_b[(size_t)(row >> 12) * N + col] + skip[idx];
                if (EPI == 2) { vv += bias_v[col]; vv = fast_gelu(vv); }
                if (EPI == 3) vv += bias_v[col] + skip[idx];
                if (OUT16) ((u16*)Cp)[idx] = f2bf(vv);
                else       ((float*)Cp)[idx] = vv;
            }
        }
    }
}

template<int WM>
__global__ __launch_bounds__(256)
void gemm_red_kernel(const u16* __restrict__ A, const float* __restrict__ W, int K,
                     const float* __restrict__ wa, const float* __restrict__ wb,
                     float* __restrict__ acc1, float* __restrict__ acc2)
{
    __shared__ u16 sA[128 * 32];
    __shared__ u16 sB[128 * 32];
    __shared__ float sred[4][2][64];
    const int t = threadIdx.x;
    const int w = t >> 6;
    const int lane = t & 63;
    const int lr = lane & 15;
    const int lk = lane >> 4;
    const int bm0 = blockIdx.x * 128;
    const int bn0 = blockIdx.y * 128;
    const int wrow = (w >> 1) * 64;
    const int wcol = (w & 1) * 64;

    f32x4 acc[4][4];
#pragma unroll
    for (int m = 0; m < 4; ++m)
#pragma unroll
        for (int n = 0; n < 4; ++n) acc[m][n] = (f32x4){0.f, 0.f, 0.f, 0.f};

    const size_t aoff = (size_t)(bm0 + (t >> 2)) * K + (t & 3) * 8;
    const size_t boff = (size_t)(bn0 + (t >> 2)) * K + (t & 3) * 8;
    const size_t rstep = (size_t)64 * K;
    u16* dA = sA + 8 * t;
    u16* dB = sB + 8 * t;

    for (int kt = 0; kt < K; kt += 32) {
        uint4 ra0, ra1, rb0, rb1;
        load_pair<true >(A, aoff + kt, rstep, ra0, ra1);
        load_pair<false>(W, boff + kt, rstep, rb0, rb1);
        __syncthreads();
        *(uint4*)dA = ra0; *(uint4*)(dA + 2048) = ra1;
        *(uint4*)dB = rb0; *(uint4*)(dB + 2048) = rb1;
        __syncthreads();
        bf16x8 af[4], bfr[4];
#pragma unroll
        for (int m = 0; m < 4; ++m)
            af[m] = *(const bf16x8*)&sA[(wrow + m * 16 + lr) * 32 + lk * 8];
#pragma unroll
        for (int n = 0; n < 4; ++n)
            bfr[n] = *(const bf16x8*)&sB[(wcol + n * 16 + lr) * 32 + lk * 8];
#pragma unroll
        for (int m = 0; m < 4; ++m)
#pragma unroll
            for (int n = 0; n < 4; ++n)
                acc[m][n] = __builtin_amdgcn_mfma_f32_16x16x32_bf16(af[m], bfr[n], acc[m][n], 0, 0, 0);
    }

    float w1v[16], w2v[16];
#pragma unroll
    for (int m = 0; m < 4; ++m)
#pragma unroll
        for (int r = 0; r < 4; ++r) {
            const int row = bm0 + wrow + m * 16 + lk * 4 + r;
            if (WM == 0) { float mm = wa[row]; w1v[m*4+r] = mm; w2v[m*4+r] = 1.f - mm; }
            else         { w1v[m*4+r] = wa[row]; w2v[m*4+r] = wb[row]; }
        }
#pragma unroll
    for (int n = 0; n < 4; ++n) {
        float s1 = 0.f, s2 = 0.f;
#pragma unroll
        for (int m = 0; m < 4; ++m)
#pragma unroll
            for (int r = 0; r < 4; ++r) {
                s1 += acc[m][n][r] * w1v[m*4+r];
                s2 += acc[m][n][r] * w2v[m*4+r];
            }
        s1 += __shfl_xor(s1, 16, 64); s1 += __shfl_xor(s1, 32, 64);
        s2 += __shfl_xor(s2, 16, 64); s2 += __shfl_xor(s2, 32, 64);
        if (lk == 0) { sred[w][0][n*16+lr] = s1; sred[w][1][n*16+lr] = s2; }
    }
    __syncthreads();
    if (t < 128) {
        const int half = t >> 6, c = t & 63;
        const float v1 = sred[half][0][c] + sred[half + 2][0][c];
        const float v2 = sred[half][1][c] + sred[half + 2][1][c];
        const int col = bn0 + half * 64 + c;
        const int b = bm0 >> 12;
        atomicAdd(&acc1[b * 512 + col], v1);
        atomicAdd(&acc2[b * 512 + col], v2);
    }
}

// ---------------- per-batch row sum of f32 (b,4096) arrays ----------------
__global__ __launch_bounds__(256)
void rowsum_kernel(const float* __restrict__ in, float* __restrict__ out)
{
    __shared__ float sred[4];
    const int b = blockIdx.x, t = threadIdx.x;
    float s = 0.f;
    for (int i = 0; i < 16; ++i) s += in[b * 4096 + t + i * 256];
    s = wsum(s);
    if ((t & 63) == 0) sred[t >> 6] = s;
    __syncthreads();
    if (t == 0) out[b] = sred[0] + sred[1] + sred[2] + sred[3];
}
__global__ __launch_bounds__(256)
void rowsum2_kernel(const float* __restrict__ in0, float* __restrict__ out0,
                    const float* __restrict__ in1, float* __restrict__ out1)
{
    __shared__ float sred[4];
    const float* in = blockIdx.y ? in1 : in0;
    float* out = blockIdx.y ? out1 : out0;
    const int b = blockIdx.x, t = threadIdx.x;
    float s = 0.f;
    for (int i = 0; i < 16; ++i) s += in[b * 4096 + t + i * 256];
    s = wsum(s);
    if ((t & 63) == 0) sred[t >> 6] = s;
    __syncthreads();
    if (t == 0) out[b] = sred[0] + sred[1] + sred[2] + sred[3];
}

// ---------------- finalize fg/bg prototypes + norms ----------------
__global__ __launch_bounds__(512)
void proto_fin_kernel(const float* __restrict__ fgacc, const float* __restrict__ bgacc,
                      const float* __restrict__ denfg, float* __restrict__ fg_pro,
                      float* __restrict__ bg_pro, float* __restrict__ nfg, float* __restrict__ nbg)
{
    __shared__ float sred[16];
    const int b = blockIdx.x, c = threadIdx.x;
    const float d = denfg[b];
    const float fg = fgacc[b * 512 + c] / (d + 5e-4f);
    const float bg = bgacc[b * 512 + c] / ((4096.f - d) + 5e-4f);
    fg_pro[b * 512 + c] = fg; bg_pro[b * 512 + c] = bg;
    float s1 = wsum(fg * fg), s2 = wsum(bg * bg);
    if ((c & 63) == 0) { sred[c >> 6] = s1; sred[8 + (c >> 6)] = s2; }
    __syncthreads();
    if (c == 0) {
        float a = 0.f, bb = 0.f;
        for (int i = 0; i < 8; ++i) { a += sred[i]; bb += sred[8 + i]; }
        nfg[b] = sqrtf(a); nbg[b] = sqrtf(bb);
    }
}

// ---------------- token cosine sims -> softmax pseudo mask ----------------
__global__ __launch_bounds__(256)
void sim_kernel(const u16* __restrict__ k, const float* __restrict__ fg_pro,
                const float* __restrict__ bg_pro, const float* __restrict__ nfg,
                const float* __restrict__ nbg, float* __restrict__ pseudo_fg,
                float* __restrict__ pm)
{
    const int lane = threadIdx.x & 63;
    const int token = blockIdx.x * 4 + (threadIdx.x >> 6);
    const int b = token >> 12, n = token & 4095;
    uint4 u = *(const uint4*)(k + (size_t)token * 512 + lane * 8);
    float kv[8]; unpack8(u, kv);
    const float* fp = fg_pro + b * 512 + lane * 8;
    const float* bp = bg_pro + b * 512 + lane * 8;
    float dfg = 0.f, dbg = 0.f, kk = 0.f;
#pragma unroll
    for (int i = 0; i < 8; ++i) { dfg += kv[i] * fp[i]; dbg += kv[i] * bp[i]; kk += kv[i] * kv[i]; }
    dfg = wsum(dfg); dbg = wsum(dbg); kk = wsum(kk);
    const float nk = fmaxf(sqrtf(kk), 1e-8f);
    const float sfg = 10.f * dfg / (nk * fmaxf(nfg[b], 1e-8f));
    const float sbg = 10.f * dbg / (nk * fmaxf(nbg[b], 1e-8f));
    const float pfg = 1.f / (1.f + expf(sbg - sfg));
    if (lane == 0) {
        pseudo_fg[token] = pfg;
        pm[(size_t)b * 8192 + 4096 + n] = pfg;
        pm[(size_t)b * 8192 + n] = 1.f - pfg;
    }
}

// ---------------- pro1/pro2 mixing ----------------
__global__ __launch_bounds__(512)
void proto2_kernel(const float* __restrict__ q1acc, const float* __restrict__ q2acc,
                   const float* __restrict__ denq1, const float* __restrict__ denq2,
                   const float* __restrict__ fg_pro, const float* __restrict__ nfg,
                   float* __restrict__ pro1, float* __restrict__ pro2)
{
    __shared__ float sred[32];
    __shared__ float s1s, s2s;
    const int b = blockIdx.x, c = threadIdx.x;
    const float q1 = q1acc[b * 512 + c] / (denq1[b] + 5e-4f);
    const float q2 = q2acc[b * 512 + c] / (denq2[b] + 5e-4f);
    const float fg = fg_pro[b * 512 + c];
    float r0 = wsum(q1 * fg), r1 = wsum(q1 * q1), r2 = wsum(q2 * fg), r3 = wsum(q2 * q2);
    const int wv = c >> 6;
    if ((c & 63) == 0) { sred[wv] = r0; sred[8 + wv] = r1; sred[16 + wv] = r2; sred[24 + wv] = r3; }
    __syncthreads();
    if (c == 0) {
        float d1 = 0.f, n1 = 0.f, d2 = 0.f, n2 = 0.f;
        for (int i = 0; i < 8; ++i) { d1 += sred[i]; n1 += sred[8+i]; d2 += sred[16+i]; n2 += sred[24+i]; }
        const float nf = fmaxf(nfg[b], 1e-8f);
        s1s = (d1 / (fmaxf(sqrtf(n1), 1e-8f) * nf) + 1.f) * 0.5f;
        s2s = (d2 / (fmaxf(sqrtf(n2), 1e-8f) * nf) + 1.f) * 0.5f;
    }
    __syncthreads();
    pro1[b * 512 + c] = s1s * fg + (1.f - s1s) * q1;
    pro2[b * 512 + c] = s2s * fg + (1.f - s2s) * q2;
}

// ---------------- scalar fold (fallback path only) ----------------
__global__ __launch_bounds__(256)
void mmcomb2_kernel(const float* __restrict__ Wfx, const float* __restrict__ Wx1,
                    const float* __restrict__ Wx2, u16* __restrict__ Mx,
                    const float* __restrict__ Wfy, const float* __restrict__ Wy1,
                    const float* __restrict__ Wy2, u16* __restrict__ My)
{
    const float* Wf = blockIdx.z ? Wfy : Wfx;
    const float* W1 = blockIdx.z ? Wy1 : Wx1;
    const float* W2 = blockIdx.z ? Wy2 : Wx2;
    u16* Mout = blockIdx.z ? My : Mx;
    const int i = blockIdx.x * 16 + threadIdx.x;
    const int o = blockIdx.y * 16 + threadIdx.y;
    float s = 0.f;
    for (int j = 0; j < 512; ++j) {
        s += Wf[o * 1024 + j]       * W1[j * 1024 + i];
        s += Wf[o * 1024 + 512 + j] * W2[j * 1024 + i];
    }
    Mout[o * 512 + i] = f2bf(s);
}

// ---------------- batched tvec ----------------
__global__ __launch_bounds__(512)
void tvec4_kernel(const float* __restrict__ Wx1, const float* __restrict__ Wx2,
                  const float* __restrict__ Wy1, const float* __restrict__ Wy2,
                  const float* __restrict__ pro1, const float* __restrict__ pro2,
                  float* __restrict__ t1x, float* __restrict__ t2x,
                  float* __restrict__ t1y, float* __restrict__ t2y)
{
    const int z = blockIdx.z;
    const float* W = (z == 0) ? Wx1 : (z == 1) ? Wx2 : (z == 2) ? Wy1 : Wy2;
    const float* p = (z & 1) ? pro2 : pro1;
    float* tout = (z == 0) ? t1x : (z == 1) ? t2x : (z == 2) ? t1y : t2y;
    const int lane = threadIdx.x & 63;
    const int j = blockIdx.x * 8 + (threadIdx.x >> 6);
    const int b = blockIdx.y;
    const float* wr = W + (size_t)j * 1024 + 512 + lane * 8;
    const float* pr = p + b * 512 + lane * 8;
    float4 w0 = *(const float4*)wr, w1 = *(const float4*)(wr + 4);
    float4 p0 = *(const float4*)pr, p1 = *(const float4*)(pr + 4);
    float s = w0.x*p0.x + w0.y*p0.y + w0.z*p0.z + w0.w*p0.w
            + w1.x*p1.x + w1.y*p1.y + w1.z*p1.z + w1.w*p1.w;
    s = wsum(s);
    if (lane == 0) tout[b * 512 + j] = s;
}

// ---------------- batched biascomb ----------------
__global__ __launch_bounds__(512)
void biascomb2_kernel(const float* __restrict__ Wfx, const float* __restrict__ Wfy,
                      const float* __restrict__ t1x, const float* __restrict__ t2x,
                      const float* __restrict__ t1y, const float* __restrict__ t2y,
                      float* __restrict__ bias_x, float* __restrict__ bias_y)
{
    const int z = blockIdx.z;
    const float* Wf = z ? Wfy : Wfx;
    const float* t1 = z ? t1y : t1x;
    const float* t2 = z ? t2y : t2x;
    float* bias = z ? bias_y : bias_x;
    const int lane = threadIdx.x & 63;
    const int o = blockIdx.x * 8 + (threadIdx.x >> 6);
    const int b = blockIdx.y;
    const float* w1 = Wf + (size_t)o * 1024 + lane * 8;
    const float* tp1 = t1 + b * 512 + lane * 8;
    const float* tp2 = t2 + b * 512 + lane * 8;
    float s = 0.f;
#pragma unroll
    for (int h = 0; h < 2; ++h) {
        const float* wv = w1 + h * 512;
        const float* tp = h ? tp2 : tp1;
        float4 a0 = *(const float4*)wv, a1 = *(const float4*)(wv + 4);
        float4 b0 = *(const float4*)tp, b1 = *(const float4*)(tp + 4);
        s += a0.x*b0.x + a0.y*b0.y + a0.z*b0.z + a0.w*b0.w
           + a1.x*b1.x + a1.y*b1.y + a1.z*b1.z + a1.w*b1.w;
    }
    s = wsum(s);
    if (lane == 0) bias[b * 512 + o] = s;
}

extern "C" void kernel_launch(void* const* d_in, const int* in_sizes, int n_in,
                              void* d_out, int out_size, void* d_ws, size_t ws_size,
                              hipStream_t stream)
{
    const float* x   = (const float*)d_in[0];
    const float* y   = (const float*)d_in[1];
    const float* mask= (const float*)d_in[2];
    const float* pp  = (const float*)d_in[3];
    const float* g1  = (const float*)d_in[4];
    const float* be1 = (const float*)d_in[5];
    const float* g2  = (const float*)d_in[6];
    const float* be2 = (const float*)d_in[7];
    const float* Wq  = (const float*)d_in[8];
    const float* Wk  = (const float*)d_in[9];
    const float* Wv  = (const float*)d_in[10];
    const float* Wx1 = (const float*)d_in[11];
    const float* Wx2 = (const float*)d_in[12];
    const float* Wfx = (const float*)d_in[13];
    const float* Wy1 = (const float*)d_in[14];
    const float* Wy2 = (const float*)d_in[15];
    const float* Wfy = (const float*)d_in[16];
    const float* W1x = (const float*)d_in[17];
    const float* b1x = (const float*)d_in[18];
    const float* W2x = (const float*)d_in[19];
    const float* b2x = (const float*)d_in[20];
    const float* W1y = (const float*)d_in[21];
    const float* b1y = (const float*)d_in[22];
    const float* W2y = (const float*)d_in[23];
    const float* b2y = (const float*)d_in[24];

    if (ws_size < 69206016u) return;
    const bool fast = ws_size >= 78643200u;
    const bool huge = ws_size >= 145752064u;

    float* outx = (float*)d_out;
    float* outy = outx + 16777216;
    float* pmf  = outx + 33554432;

    char* wsb = (char*)d_ws;
    float* fsm = (float*)wsb;
    float* fgacc  = fsm;
    float* bgacc  = fsm + 4096;
    float* q1acc  = fsm + 8192;
    float* q2acc  = fsm + 12288;
    float* denq1  = fsm + 16384;
    float* denfg  = fsm + 16392;
    float* denq2  = fsm + 16400;
    float* nfg    = fsm + 16408;
    float* nbg    = fsm + 16416;
    float* fg_pro = fsm + 16424;
    float* bg_pro = fsm + 20520;
    float* pro1   = fsm + 24616;
    float* pro2   = fsm + 28712;
    float* t1x    = fsm + 32808;
    float* t2x    = fsm + 36904;
    float* t1y    = fsm + 41000;
    float* t2y    = fsm + 45096;
    float* bias_x = fsm + 49192;
    float* bias_y = fsm + 53288;
    float* pseudo = fsm + 57384;

    hipMemsetAsync(fsm, 0, 65568, stream);

    if (fast) {
        u16* Mx   = (u16*)(wsb + 0x60000);
        u16* My   = (u16*)(wsb + 0xE0000);
        u16* Wqb  = (u16*)(wsb + 0x160000);
        u16* Wkb  = (u16*)(wsb + 0x1E0000);
        u16* Wvb  = (u16*)(wsb + 0x260000);
        u16* W1xb = (u16*)(wsb + 0x2E0000);
        u16* W2xb = (u16*)(wsb + 0x4E0000);
        u16* W1yb = (u16*)(wsb + 0x6E0000);
        u16* W2yb = (u16*)(wsb + 0x8E0000);
        u16* WS0  = (u16*)(wsb + 0xB00000);
        u16* WS1  = WS0 + 16777216;
        u16* WS2  = WS1 + 16777216;

        u16* OX0 = (u16*)outx;               // raw x bf16 (first half of outx)
        u16* OX1 = OX0 + 16777216;           // k, then ym
        u16* OY  = (u16*)outy;               // raw y bf16, then hidden-x

        // transient M-fold buffers in WS0 (dead before LN1 writes WS0)
        u16* Wfxb = WS0;
        u16* Wfyb = WS0 + 524288;
        u16* Wtx  = WS0 + 1048576;
        u16* Wty  = WS0 + 1572864;

        cvt3_kernel<<<dim3(128, 3), 256, 0, stream>>>(Wq, Wk, Wv, Wqb, Wkb, Wvb, 32768);
        cvt4_kernel<<<dim3(512, 4), 256, 0, stream>>>(W1x, W2x, W1y, W2y, W1xb, W2xb, W1yb, W2yb, 131072);
        cvt2_kernel<<<dim3(256, 2), 256, 0, stream>>>(Wfx, Wfy, Wfxb, Wfyb, 65536);
        wtrans_kernel<<<dim3(16, 16, 4), dim3(32, 8), 0, stream>>>(Wx1, Wx2, Wy1, Wy2, Wtx, Wty);
        gemm2z_kernel<0, true><<<dim3(4, 4, 2), 256, 0, stream>>>(
            Wfxb, Wtx, Mx, nullptr, nullptr,
            Wfyb, Wty, My, nullptr, nullptr, 512, 1024);

        // LN1 batched: x -> WS0 (+raw OX0), y -> WS1 (+raw OY)
        ln2_kernel<false, true><<<dim3(8192, 2), 256, 0, stream>>>(x, WS0, OX0, y, WS1, OY, g1, be1);

        rowsum2_kernel<<<dim3(8, 2), 256, 0, stream>>>(mask, denfg, pp, denq2);

        // q-reduction (z=0) and k GEMM (z=1) batched — independent inputs/outputs
        qk_mix_kernel<<<dim3(256, 2, 2), 512, 0, stream>>>(
            WS1, Wqb, mask, fgacc, bgacc,
            WS0, Wkb, OX1, 512, 512);

        proto_fin_kernel<<<8, 512, 0, stream>>>(fgacc, bgacc, denfg, fg_pro, bg_pro, nfg, nbg);
        sim_kernel<<<8192, 256, 0, stream>>>(OX1, fg_pro, bg_pro, nfg, nbg, pseudo, pmf);
        rowsum_kernel<<<8, 256, 0, stream>>>(pseudo, denq1);

        gemm3_red_kernel<1><<<dim3(256, 2), 512, 0, stream>>>(WS0, Wvb, 512, pseudo, pp, q1acc, q2acc);
        proto2_kernel<<<8, 512, 0, stream>>>(q1acc, q2acc, denq1, denq2, fg_pro, nfg, pro1, pro2);

        tvec4_kernel<<<dim3(64, 8, 4), 512, 0, stream>>>(Wx1, Wx2, Wy1, Wy2, pro1, pro2, t1x, t2x, t1y, t2y);
        biascomb2_kernel<<<dim3(64, 8, 2), 512, 0, stream>>>(Wfx, Wfy, t1x, t2x, t1y, t2y, bias_x, bias_y);

        // merges batched: xm -> WS0 (xn dead), ym -> OX1 (k dead)
        gemm3z_kernel<1, true><<<dim3(256, 2, 2), 512, 0, stream>>>(
            OX0, Mx, WS0, bias_x, nullptr, x,
            OY,  My, OX1, bias_y, nullptr, y, 512, 512);

        // LN2 sequential: lx: WS0 -> WS1; ly: OX1 -> WS0
        ln_kernel<true, false><<<8192, 256, 0, stream>>>(WS0, WS1, g2, be2, nullptr);
        ln_kernel<true, false><<<8192, 256, 0, stream>>>(OX1, WS0, g2, be2, nullptr);

        // x-MLP: 2 chunks of 16384 rows, hidden in OY (raw y dead); outx overwrites OX0/OX1 (both dead)
        for (int ch = 0; ch < 2; ++ch) {
            const size_t ro = (size_t)ch * 16384 * 512;
            gemm3_kernel<2, true><<<dim3(128, 8), 512, 0, stream>>>(WS1 + ro, W1xb, OY, 2048, 512, nullptr, b1x, nullptr);
            gemm2_kernel<3, false><<<dim3(128, 4), 256, 0, stream>>>(OY, W2xb, outx + ro, 512, 2048, nullptr, b2x, x + ro);
        }

        // y-MLP: ly in WS0
        if (huge) {
            for (int ch = 0; ch < 2; ++ch) {
                const size_t ro = (size_t)ch * 16384 * 512;
                gemm3_kernel<2, true><<<dim3(128, 8), 512, 0, stream>>>(WS0 + ro, W1yb, WS2, 2048, 512, nullptr, b1y, nullptr);
                gemm2_kernel<3, false><<<dim3(128, 4), 256, 0, stream>>>(WS2, W2yb, outy + ro, 512, 2048, nullptr, b2y, y + ro);
            }
        } else {
            for (int ch = 0; ch < 4; ++ch) {
                const size_t ro = (size_t)ch * 8192 * 512;
                gemm3_kernel<2, true><<<dim3(64, 8), 512, 0, stream>>>(WS0 + ro, W1yb, WS1, 2048, 512, nullptr, b1y, nullptr);
                gemm2_kernel<3, false><<<dim3(64, 4), 256, 0, stream>>>(WS1, W2yb, outy + ro, 512, 2048, nullptr, b2y, y + ro);
            }
        }
    } else {
        // ---- fallback: round-4 path ----
        u16* Mx  = (u16*)(wsb + 360608);
        u16* My  = (u16*)(wsb + 884896);
        u16* WS0 = (u16*)(wsb + 2097152);
        u16* WS1 = (u16*)(wsb + 35651584);

        ln_kernel<false, false><<<8192, 256, 0, stream>>>(x, WS0, g1, be1, nullptr);
        ln_kernel<false, false><<<8192, 256, 0, stream>>>(y, WS1, g1, be1, nullptr);

        dim3 g512(256, 4);
        gemm_red_kernel<0><<<g512, 256, 0, stream>>>(WS1, Wq, 512, mask, nullptr, fgacc, bgacc);
        rowsum_kernel<<<8, 256, 0, stream>>>(mask, denfg);
        rowsum_kernel<<<8, 256, 0, stream>>>(pp, denq2);
        proto_fin_kernel<<<8, 512, 0, stream>>>(fgacc, bgacc, denfg, fg_pro, bg_pro, nfg, nbg);

        gemm_kernel<0, true, false, true><<<g512, 256, 0, stream>>>(WS0, Wk, WS1, 512, 512, nullptr, nullptr, nullptr);
        sim_kernel<<<8192, 256, 0, stream>>>(WS1, fg_pro, bg_pro, nfg, nbg, pseudo, pmf);
        rowsum_kernel<<<8, 256, 0, stream>>>(pseudo, denq1);

        gemm_red_kernel<1><<<g512, 256, 0, stream>>>(WS0, Wv, 512, pseudo, pp, q1acc, q2acc);
        proto2_kernel<<<8, 512, 0, stream>>>(q1acc, q2acc, denq1, denq2, fg_pro, nfg, pro1, pro2);

        mmcomb2_kernel<<<dim3(32, 32, 2), dim3(16, 16), 0, stream>>>(Wfx, Wx1, Wx2, Mx, Wfy, Wy1, Wy2, My);
        tvec4_kernel<<<dim3(64, 8, 4), 512, 0, stream>>>(Wx1, Wx2, Wy1, Wy2, pro1, pro2, t1x, t2x, t1y, t2y);
        biascomb2_kernel<<<dim3(64, 8, 2), 512, 0, stream>>>(Wfx, Wfy, t1x, t2x, t1y, t2y, bias_x, bias_y);

        gemm_kernel<1, false, true, true><<<g512, 256, 0, stream>>>(x, Mx, WS0, 512, 512, bias_x, nullptr, x);
        ln_kernel<true, false><<<8192, 256, 0, stream>>>(WS0, WS1, g2, be2, nullptr);
        for (int ch = 0; ch < 4; ++ch) {
            const size_t ro = (size_t)ch * 8192 * 512;
            gemm_kernel<2, true, false, true><<<dim3(64, 16), 256, 0, stream>>>(WS1 + ro, W1x, WS0, 2048, 512, nullptr, b1x, nullptr);
            gemm_kernel<3, true, false, false><<<dim3(64, 4), 256, 0, stream>>>(WS0, W2x, outx + ro, 512, 2048, nullptr, b2x, x + ro);
        }
        gemm_kernel<1, false, true, true><<<g512, 256, 0, stream>>>(y, My, WS0, 512, 512, bias_y, nullptr, y);
        ln_kernel<true, false><<<8192, 256, 0, stream>>>(WS0, WS1, g2, be2, nullptr);
        for (int ch = 0; ch < 4; ++ch) {
            const size_t ro = (size_t)ch * 8192 * 512;
            gemm_kernel<2, true, false, true><<<dim3(64, 16), 256, 0, stream>>>(WS1 + ro, W1y, WS0, 2048, 512, nullptr, b1y, nullptr);
            gemm_kernel<3, true, false, false><<<dim3(64, 4), 256, 0, stream>>>(WS0, W2y, outy + ro, 512, 2048, nullptr, b2y, y + ro);
        }
    }
    (void)in_sizes; (void)n_in; (void)out_size;
}